// Round 2
// baseline (13669.189 us; speedup 1.0000x reference)
//
#include <hip/hip_runtime.h>

#define NN 100000
#define NE 800000
#define NG 4096
#define HH 97
#define HP 128

typedef unsigned short u16;
typedef unsigned int u32;

__device__ __forceinline__ float sigm_(float x){ return 1.f/(1.f+__expf(-x)); }
__device__ __forceinline__ float lrelu01_(float x){ return x>0.f? x : 0.01f*x; }
__device__ __forceinline__ float tanh_(float t){ float e2=__expf(2.f*t); return 1.f-2.f/(e2+1.f); }
__device__ __forceinline__ float b2f(u16 u){ union{u32 i; float f;} t; t.i=(u32)u<<16; return t.f; }
__device__ __forceinline__ u16 f2b(float x){ union{float f; u32 i;} t; t.f=x; u32 r=t.i+0x7FFFu+((t.i>>16)&1u); return (u16)(r>>16); }

// ---------------- packing kernels (fp32 weights, zero-padded to HP/384/512) ----------------
__global__ void k_pack_convw(const float* __restrict__ Wk, const float* __restrict__ Wq,
                             const float* __restrict__ Wv, const float* __restrict__ Ws,
                             float* __restrict__ out){
  int idx = blockIdx.x*256 + threadIdx.x;
  if (idx >= 7*128*512) return;
  int l = idx / 65536, r = idx % 65536;
  int k = r >> 9, c = r & 511;
  int m = c >> 7, h = c & 127;
  float v = 0.f;
  if (k < HH && h < HH){
    const float* W = (m==0)? Wk : (m==1)? Wq : (m==2)? Wv : Ws;
    v = W[l*9409 + k*97 + h];
  }
  out[idx] = v;
}

__global__ void k_pack_convb(const float* __restrict__ bk, const float* __restrict__ bq,
                             const float* __restrict__ bv, const float* __restrict__ bs,
                             float* __restrict__ out){
  int idx = blockIdx.x*256 + threadIdx.x;
  if (idx >= 7*512) return;
  int l = idx >> 9, c = idx & 511;
  int m = c >> 7, h = c & 127;
  float v = 0.f;
  if (h < HH){
    const float* B = (m==0)? bk : (m==1)? bq : (m==2)? bv : bs;
    v = B[l*97 + h];
  }
  out[idx] = v;
}

__global__ void k_pack_gruw(const float* __restrict__ gih, const float* __restrict__ ghh,
                            const float* __restrict__ mih, const float* __restrict__ mhh,
                            float* __restrict__ oih, float* __restrict__ ohh){
  int idx = blockIdx.x*256 + threadIdx.x;
  if (idx >= 8*128*384) return;
  int l = idx / 49152, r = idx % 49152;
  int k = r / 384, g3 = r % 384;
  int g = g3 / 3, j = g3 % 3;
  float vi = 0.f, vh = 0.f;
  if (k < HH && g < HH){
    const float* si = (l < 7)? gih + (size_t)l*28227 : mih;
    const float* sh = (l < 7)? ghh + (size_t)l*28227 : mhh;
    vi = si[k*291 + j*97 + g];
    vh = sh[k*291 + j*97 + g];
  }
  oih[idx] = vi; ohh[idx] = vh;
}

__global__ void k_pack_grub(const float* __restrict__ gbi, const float* __restrict__ gbh,
                            const float* __restrict__ mbi, const float* __restrict__ mbh,
                            float* __restrict__ obi, float* __restrict__ obh){
  int idx = blockIdx.x*256 + threadIdx.x;
  if (idx >= 8*384) return;
  int l = idx / 384, g3 = idx % 384;
  int g = g3 / 3, j = g3 % 3;
  float vi = 0.f, vh = 0.f;
  if (g < HH){
    const float* si = (l < 7)? gbi + l*291 : mbi;
    const float* sh = (l < 7)? gbh + l*291 : mbh;
    vi = si[j*97 + g];
    vh = sh[j*97 + g];
  }
  obi[idx] = vi; obh[idx] = vh;
}

// contiguous region: GATWP[16384] ASRCP[128] ADSTP[128] GBP[128] W2P[128] ZB[512]
__global__ void k_pack_misc(const float* __restrict__ gatW, const float* __restrict__ asrc,
                            const float* __restrict__ adst, const float* __restrict__ gatb,
                            const float* __restrict__ l2W, float* __restrict__ out){
  int idx = blockIdx.x*256 + threadIdx.x;
  if (idx < 16384){
    int k = idx >> 7, h = idx & 127;
    out[idx] = (k < HH && h < HH)? gatW[k*97 + h] : 0.f;
  } else if (idx < 16512){
    int h = idx - 16384; out[idx] = (h < HH)? asrc[h] : 0.f;
  } else if (idx < 16640){
    int h = idx - 16512; out[idx] = (h < HH)? adst[h] : 0.f;
  } else if (idx < 16768){
    int h = idx - 16640; out[idx] = (h < HH)? gatb[h] : 0.f;
  } else if (idx < 16896){
    int h = idx - 16768; out[idx] = (h < HH)? l2W[h] : 0.f;
  } else if (idx < 17408){
    out[idx] = 0.f;
  }
}

// ---------------- graph preprocessing ----------------
__global__ void k_seg(const int* __restrict__ batch, int* __restrict__ seg){
  int g = blockIdx.x*blockDim.x + threadIdx.x;
  if (g > NG) return;
  int lo = 0, hi = NN;
  while (lo < hi){ int mid = (lo+hi) >> 1; if (batch[mid] < g) lo = mid+1; else hi = mid; }
  seg[g] = lo;
}

// ---------------- lin1 ----------------
__global__ __launch_bounds__(256) void k_lin1(const float* __restrict__ x,
    const float* __restrict__ W, const float* __restrict__ b, u16* __restrict__ X0){
  int idx = blockIdx.x*256 + threadIdx.x;
  int n = idx >> 7, c = idx & 127;
  float v = 0.f;
  if (c < HH){
    v = b[c];
    #pragma unroll
    for (int k = 0; k < 9; ++k) v += x[n*9 + k]*W[k*HH + c];
    v = lrelu01_(v);
  }
  X0[(size_t)n*HP + c] = f2b(v);
}

// ---------------- tiled GEMM: C[M][ncols] = bf16(A)[M][128] @ Wp[128][ncols] + bias --------
// grid (M/32, ncols/128), 256 threads, 4x4 per-thread tile.
// column-block bn<3 -> bf16 store to Cb (row stride ldc); bn==3 -> fp32 store to Sf (stride HP)
__global__ __launch_bounds__(256) void k_gemm(const u16* __restrict__ A,
    const float* __restrict__ Wp, const float* __restrict__ bias,
    u16* __restrict__ Cb, int ldc, float* __restrict__ Sf, int ncols){
  int bm = blockIdx.x, bn = blockIdx.y;
  int tid = threadIdx.x;
  int ct = tid & 31, rt = tid >> 5;
  __shared__ float As[32][32];
  __shared__ float Bs[128][36];
  float acc[4][4] = {};
  int row0 = bm*32;
  for (int kc = 0; kc < 4; ++kc){
    { int r = tid >> 3, k4 = (tid & 7) << 2;
      ushort4 u = *(const ushort4*)(A + (size_t)(row0+r)*HP + kc*32 + k4);
      As[r][k4+0]=b2f(u.x); As[r][k4+1]=b2f(u.y); As[r][k4+2]=b2f(u.z); As[r][k4+3]=b2f(u.w); }
    { int c4 = (tid & 31) << 2, kk0 = tid >> 5;
      #pragma unroll
      for (int p = 0; p < 4; ++p){
        int k = kk0 + p*8;
        float4 bv = *(const float4*)(Wp + (size_t)(kc*32+k)*ncols + bn*128 + c4);
        Bs[c4+0][k]=bv.x; Bs[c4+1][k]=bv.y; Bs[c4+2][k]=bv.z; Bs[c4+3][k]=bv.w;
      } }
    __syncthreads();
    #pragma unroll
    for (int k0 = 0; k0 < 8; ++k0){
      float4 a4[4], b4[4];
      #pragma unroll
      for (int r2 = 0; r2 < 4; ++r2) a4[r2] = *(const float4*)&As[rt + r2*8][k0<<2];
      #pragma unroll
      for (int c2 = 0; c2 < 4; ++c2) b4[c2] = *(const float4*)&Bs[ct + c2*32][k0<<2];
      #pragma unroll
      for (int r2 = 0; r2 < 4; ++r2)
        #pragma unroll
        for (int c2 = 0; c2 < 4; ++c2)
          acc[r2][c2] += a4[r2].x*b4[c2].x + a4[r2].y*b4[c2].y + a4[r2].z*b4[c2].z + a4[r2].w*b4[c2].w;
    }
    __syncthreads();
  }
  #pragma unroll
  for (int c2 = 0; c2 < 4; ++c2){
    int col = bn*128 + ct + c2*32;
    float bv = bias[col];
    #pragma unroll
    for (int r2 = 0; r2 < 4; ++r2){
      int row = row0 + rt + r2*8;
      float v = acc[r2][c2] + bv;
      if (bn < 3) Cb[(size_t)row*ldc + col] = f2b(v);
      else        Sf[(size_t)row*HP + (ct + c2*32)] = v;
    }
  }
}

// ---------------- edge message + fp32 atomic scatter into S ----------------
__global__ __launch_bounds__(256) void k_edge(const u16* __restrict__ kqv,
    float* __restrict__ S, const int* __restrict__ src, const int* __restrict__ dst){
  int t = blockIdx.x*256 + threadIdx.x;
  int e = t >> 7, c = t & 127;
  if (c >= HH) return;
  int s = src[e], d = dst[e];
  float kv = b2f(kqv[(size_t)d*384 + c]);
  float qv = b2f(kqv[(size_t)s*384 + 128 + c]);
  float vv = b2f(kqv[(size_t)s*384 + 256 + c]);
  atomicAdd(&S[(size_t)d*HP + c], vv * sigm_(kv + qv));
}

// ---------------- elu (+ optional BN) in-place on S ----------------
__global__ __launch_bounds__(256) void k_elubn(float* __restrict__ S,
    const float* __restrict__ gamma, const float* __restrict__ beta,
    const float* __restrict__ mean, const float* __restrict__ var, int layer){
  int idx = blockIdx.x*256 + threadIdx.x;
  int n = idx >> 7, c = idx & 127;
  if (c >= HH) return;
  float* p = S + (size_t)n*HP + c;
  float v = *p;
  v = v > 0.f ? v : (__expf(v) - 1.f);
  if (layer > 0){
    int b = (layer-1)*97 + c;
    float sc = gamma[b]*rsqrtf(var[b] + 1e-5f);
    v = (v - mean[b])*sc + beta[b];
  }
  *p = v;
}

// ---------------- fused GRU: Xout = bf16(relu(gru(Hin fp32, Xin bf16))) ----------------
// Wih/Whh packed [128][384] gate-interleaved (g*3+j), grid (M/32, 4)
__global__ __launch_bounds__(256) void k_gru(const float* __restrict__ Hin,
    const u16* __restrict__ Xin,
    const float* __restrict__ Wih, const float* __restrict__ Whh,
    const float* __restrict__ bih, const float* __restrict__ bhh,
    u16* __restrict__ Xout){
  int bm = blockIdx.x, gb = blockIdx.y;
  int tid = threadIdx.x;
  int ct = tid & 31, rt = tid >> 5;
  __shared__ float Ah[32][32], Ax[32][32];
  __shared__ float Bi[96][36], Bh[96][36];
  float acc[4][6] = {};
  int row0 = bm*32;
  for (int kc = 0; kc < 4; ++kc){
    { int r = tid >> 3, k4 = (tid & 7) << 2;
      *(float4*)&Ah[r][k4] = *(const float4*)(Hin + (size_t)(row0+r)*HP + kc*32 + k4);
      ushort4 u = *(const ushort4*)(Xin + (size_t)(row0+r)*HP + kc*32 + k4);
      Ax[r][k4+0]=b2f(u.x); Ax[r][k4+1]=b2f(u.y); Ax[r][k4+2]=b2f(u.z); Ax[r][k4+3]=b2f(u.w); }
    #pragma unroll
    for (int p = 0; p < 12; ++p){
      int idx = tid + p*256;
      int kk = idx / 96, c = idx % 96;
      Bi[c][kk] = Wih[(size_t)(kc*32+kk)*384 + gb*96 + c];
      Bh[c][kk] = Whh[(size_t)(kc*32+kk)*384 + gb*96 + c];
    }
    __syncthreads();
    #pragma unroll
    for (int k0 = 0; k0 < 8; ++k0){
      float4 bi3[3], bh3[3], ah[4], ax[4];
      #pragma unroll
      for (int j = 0; j < 3; ++j){
        bi3[j] = *(const float4*)&Bi[ct*3+j][k0<<2];
        bh3[j] = *(const float4*)&Bh[ct*3+j][k0<<2];
      }
      #pragma unroll
      for (int r2 = 0; r2 < 4; ++r2){
        ah[r2] = *(const float4*)&Ah[rt + r2*8][k0<<2];
        ax[r2] = *(const float4*)&Ax[rt + r2*8][k0<<2];
      }
      #pragma unroll
      for (int r2 = 0; r2 < 4; ++r2){
        #pragma unroll
        for (int j = 0; j < 3; ++j){
          acc[r2][j]   += ah[r2].x*bi3[j].x + ah[r2].y*bi3[j].y + ah[r2].z*bi3[j].z + ah[r2].w*bi3[j].w;
          acc[r2][3+j] += ax[r2].x*bh3[j].x + ax[r2].y*bh3[j].y + ax[r2].z*bh3[j].z + ax[r2].w*bh3[j].w;
        }
      }
    }
    __syncthreads();
  }
  int g = gb*32 + ct;
  int b0 = gb*96 + ct*3;
  float bi0 = bih[b0], bi1 = bih[b0+1], bi2 = bih[b0+2];
  float bh0 = bhh[b0], bh1 = bhh[b0+1], bh2 = bhh[b0+2];
  #pragma unroll
  for (int r2 = 0; r2 < 4; ++r2){
    int row = row0 + rt + r2*8;
    float ir = acc[r2][0]+bi0, iz = acc[r2][1]+bi1, inn = acc[r2][2]+bi2;
    float hr = acc[r2][3]+bh0, hz = acc[r2][4]+bh1, hn = acc[r2][5]+bh2;
    float rr = sigm_(ir + hr);
    float zz = sigm_(iz + hz);
    float nn2 = tanh_(inn + rr*hn);
    float xo = b2f(Xin[(size_t)row*HP + g]);
    float v = (1.f - zz)*nn2 + zz*xo;
    Xout[(size_t)row*HP + g] = f2b(fmaxf(v, 0.f));
  }
}

// ---------------- readout ----------------
__global__ __launch_bounds__(128) void k_pool(const int* __restrict__ seg,
    const u16* __restrict__ x, u16* __restrict__ out){
  int g = blockIdx.x, tid = threadIdx.x;
  int lo = seg[g], hi = seg[g+1];
  float acc = 0.f;
  for (int n = lo; n < hi; ++n) acc += b2f(x[(size_t)n*HP + tid]);
  out[(size_t)g*HP + tid] = f2b(fmaxf(acc, 0.f));
}

__global__ __launch_bounds__(256) void k_as(const u16* __restrict__ xs,
    const float* __restrict__ asrcp, float* __restrict__ a_s){
  int t = blockIdx.x*256 + threadIdx.x;
  int n = t >> 6, lane = t & 63;
  float v = b2f(xs[(size_t)n*HP + lane])*asrcp[lane]
          + b2f(xs[(size_t)n*HP + 64 + lane])*asrcp[64 + lane];
  #pragma unroll
  for (int o = 32; o > 0; o >>= 1) v += __shfl_down(v, o);
  if (lane == 0) a_s[n] = v;
}

__global__ __launch_bounds__(128) void k_ad(const u16* __restrict__ out,
    const float* __restrict__ gatwp, const float* __restrict__ adstp, float* __restrict__ ad){
  int g = blockIdx.x, tid = threadIdx.x;
  __shared__ float so[HP];
  __shared__ float red[2];
  so[tid] = b2f(out[(size_t)g*HP + tid]);
  __syncthreads();
  float p = 0.f;
  #pragma unroll 4
  for (int k = 0; k < HP; ++k) p += so[k]*gatwp[k*HP + tid];
  float v = p * adstp[tid];
  #pragma unroll
  for (int o = 32; o > 0; o >>= 1) v += __shfl_down(v, o);
  if ((tid & 63) == 0) red[tid >> 6] = v;
  __syncthreads();
  if (tid == 0) ad[g] = red[0] + red[1];
}

#define ACAP 2048
__global__ __launch_bounds__(128) void k_attn(const int* __restrict__ seg,
    const float* __restrict__ a_s, const float* __restrict__ a_d,
    const u16* __restrict__ xs, const float* __restrict__ gbp, float* __restrict__ hg){
  int g = blockIdx.x, tid = threadIdx.x;
  int lo = seg[g], hi = seg[g+1], cnt = hi - lo;
  float ad = a_d[g];
  __shared__ float sa[ACAP];
  __shared__ float red[2];
  float mloc = -3.4e38f;
  for (int i = tid; i < cnt; i += 128){
    float al = lrelu01_(a_s[lo+i] + ad);
    if (i < ACAP) sa[i] = al;
    mloc = fmaxf(mloc, al);
  }
  #pragma unroll
  for (int o = 32; o > 0; o >>= 1) mloc = fmaxf(mloc, __shfl_down(mloc, o));
  if ((tid & 63) == 0) red[tid >> 6] = mloc;
  __syncthreads();
  float mm = fmaxf(red[0], red[1]);
  __syncthreads();
  float sloc = 0.f;
  for (int i = tid; i < cnt; i += 128){
    float al = (i < ACAP)? sa[i] : lrelu01_(a_s[lo+i] + ad);
    float e = __expf(al - mm);
    if (i < ACAP) sa[i] = e;
    sloc += e;
  }
  #pragma unroll
  for (int o = 32; o > 0; o >>= 1) sloc += __shfl_down(sloc, o);
  if ((tid & 63) == 0) red[tid >> 6] = sloc;
  __syncthreads();
  float ss = red[0] + red[1];
  float inv = (cnt > 0 && ss != 0.f)? 1.f/ss : 0.f;
  __syncthreads();
  float accv = 0.f;
  for (int i = 0; i < cnt; ++i){
    float e = (i < ACAP)? sa[i] : __expf(lrelu01_(a_s[lo+i] + ad) - mm);
    accv += (e*inv) * b2f(xs[(size_t)(lo+i)*HP + tid]);
  }
  float hgv = accv + gbp[tid];
  hg[(size_t)g*HP + tid] = hgv > 0.f ? hgv : (__expf(hgv) - 1.f);
}

__global__ __launch_bounds__(64) void k_final(const u16* __restrict__ out,
    const float* __restrict__ w2p, const float* __restrict__ l2b, float* __restrict__ y){
  int g = blockIdx.x, lane = threadIdx.x;
  float v = b2f(out[(size_t)g*HP + lane])*w2p[lane]
          + b2f(out[(size_t)g*HP + 64 + lane])*w2p[64 + lane];
  #pragma unroll
  for (int o = 32; o > 0; o >>= 1) v += __shfl_down(v, o);
  if (lane == 0) y[g] = v + l2b[0];
}

// ---------------- host ----------------
extern "C" void kernel_launch(void* const* d_in, const int* in_sizes, int n_in,
                              void* d_out, int out_size, void* d_ws, size_t ws_size,
                              hipStream_t stream){
  const float* x_in  = (const float*)d_in[0];
  const int*   ei    = (const int*)d_in[1];
  const int*   batch = (const int*)d_in[2];
  const float* lin1W = (const float*)d_in[4];
  const float* lin1b = (const float*)d_in[5];
  const float* cWk = (const float*)d_in[6];
  const float* cWq = (const float*)d_in[7];
  const float* cWv = (const float*)d_in[8];
  const float* cWs = (const float*)d_in[9];
  const float* cbk = (const float*)d_in[10];
  const float* cbq = (const float*)d_in[11];
  const float* cbv = (const float*)d_in[12];
  const float* cbs = (const float*)d_in[13];
  const float* gWih = (const float*)d_in[14];
  const float* gWhh = (const float*)d_in[15];
  const float* gbih = (const float*)d_in[16];
  const float* gbhh = (const float*)d_in[17];
  const float* bng = (const float*)d_in[18];
  const float* bnb = (const float*)d_in[19];
  const float* bnm = (const float*)d_in[20];
  const float* bnv = (const float*)d_in[21];
  const float* gatW  = (const float*)d_in[22];
  const float* gasrc = (const float*)d_in[23];
  const float* gadst = (const float*)d_in[24];
  const float* gatb  = (const float*)d_in[25];
  const float* mWih = (const float*)d_in[26];
  const float* mWhh = (const float*)d_in[27];
  const float* mbih = (const float*)d_in[28];
  const float* mbhh = (const float*)d_in[29];
  const float* l2W = (const float*)d_in[30];
  const float* l2b = (const float*)d_in[31];
  const int* src = ei;
  const int* dst = ei + NE;

  char* base = (char*)d_ws;
  size_t off = 0;
  auto alloc = [&](size_t nbytes)->char*{
    char* p = base + off; off = (off + nbytes + 255) & ~(size_t)255; return p; };

  float* WCONVP = (float*)alloc((size_t)7*128*512*4);
  float* BCONVP = (float*)alloc(7*512*4);
  float* WIHP   = (float*)alloc((size_t)8*128*384*4);
  float* WHHP   = (float*)alloc((size_t)8*128*384*4);
  float* BIHP   = (float*)alloc(8*384*4);
  float* BHHP   = (float*)alloc(8*384*4);
  float* GATWP  = (float*)alloc(17408*4);
  float* ASRCP = GATWP + 16384;
  float* ADSTP = GATWP + 16512;
  float* GBP   = GATWP + 16640;
  float* W2P   = GATWP + 16768;
  float* ZB    = GATWP + 16896;
  u16*  X0  = (u16*)alloc((size_t)NN*HP*2);
  u16*  X1  = (u16*)alloc((size_t)NN*HP*2);
  u16*  KQV = (u16*)alloc((size_t)NN*384*2);
  float* S  = (float*)alloc((size_t)NN*HP*4);
  float* AS_ = (float*)alloc((size_t)NN*4);
  float* AD_ = (float*)alloc((size_t)NG*4);
  u16*  OUTA = (u16*)alloc((size_t)NG*HP*2);
  u16*  OUTB = (u16*)alloc((size_t)NG*HP*2);
  float* HG  = (float*)alloc((size_t)NG*HP*4);
  int*  SEG  = (int*)alloc((size_t)(NG+1)*4);

  if (ws_size < off){
    // workspace too small for this layout: fail cleanly (diagnostic), no OOB
    hipMemsetAsync(d_out, 0, (size_t)out_size*sizeof(float), stream);
    return;
  }

  k_pack_convw<<<(7*128*512+255)/256,256,0,stream>>>(cWk,cWq,cWv,cWs,WCONVP);
  k_pack_convb<<<(7*512+255)/256,256,0,stream>>>(cbk,cbq,cbv,cbs,BCONVP);
  k_pack_gruw<<<(8*128*384+255)/256,256,0,stream>>>(gWih,gWhh,mWih,mWhh,WIHP,WHHP);
  k_pack_grub<<<(8*384+255)/256,256,0,stream>>>(gbih,gbhh,mbih,mbhh,BIHP,BHHP);
  k_pack_misc<<<68,256,0,stream>>>(gatW,gasrc,gadst,gatb,l2W,GATWP);
  k_lin1<<<(NN*HP)/256,256,0,stream>>>(x_in,lin1W,lin1b,X0);
  k_seg<<<(NG+1+255)/256,256,0,stream>>>(batch,SEG);

  for (int l = 0; l < 7; ++l){
    u16* Xin  = (l & 1)? X1 : X0;
    u16* Xout = (l & 1)? X0 : X1;
    k_gemm<<<dim3(NN/32,4),256,0,stream>>>(Xin, WCONVP + (size_t)l*65536, BCONVP + l*512,
                                           KQV, 384, S, 512);
    k_edge<<<NE/2,256,0,stream>>>(KQV, S, src, dst);
    k_elubn<<<(NN*HP)/256,256,0,stream>>>(S, bng, bnb, bnm, bnv, l);
    k_gru<<<dim3(NN/32,4),256,0,stream>>>(S, Xin,
        WIHP + (size_t)l*49152, WHHP + (size_t)l*49152, BIHP + l*384, BHHP + l*384, Xout);
  }
  u16* XF = X1;  // after 7 layers (l=6 even: X0 -> X1)

  k_pool<<<NG,128,0,stream>>>(SEG, XF, OUTA);
  u16* XS = KQV;  // reuse as [NN][128] bf16
  k_gemm<<<dim3(NN/32,1),256,0,stream>>>(XF, GATWP, ZB, XS, 128, (float*)nullptr, 128);
  k_as<<<(NN*64)/256,256,0,stream>>>(XS, ASRCP, AS_);

  u16* cur = OUTA; u16* nxt = OUTB;
  for (int s = 0; s < 7; ++s){
    k_ad<<<NG,128,0,stream>>>(cur, GATWP, ADSTP, AD_);
    k_attn<<<NG,128,0,stream>>>(SEG, AS_, AD_, XS, GBP, HG);
    k_gru<<<dim3(NG/32,4),256,0,stream>>>(HG, cur,
        WIHP + (size_t)7*49152, WHHP + (size_t)7*49152, BIHP + 7*384, BHHP + 7*384, nxt);
    u16* t = cur; cur = nxt; nxt = t;
  }
  k_final<<<NG,64,0,stream>>>(cur, W2P, l2b, (float*)d_out);
}

// Round 3
// 6079.677 us; speedup vs baseline: 2.2483x; 2.2483x over previous
//
#include <hip/hip_runtime.h>

#define NN 100000
#define NE 800000
#define NG 4096
#define HH 97
#define HP 128

typedef unsigned short u16;
typedef unsigned int u32;
typedef __attribute__((ext_vector_type(8))) short short8v;
typedef __attribute__((ext_vector_type(4))) float f32x4;

__device__ __forceinline__ float sigm_(float x){ return 1.f/(1.f+__expf(-x)); }
__device__ __forceinline__ float lrelu01_(float x){ return x>0.f? x : 0.01f*x; }
__device__ __forceinline__ float tanh_(float t){ float e2=__expf(2.f*t); return 1.f-2.f/(e2+1.f); }
__device__ __forceinline__ float b2f(u16 u){ union{u32 i; float f;} t; t.i=(u32)u<<16; return t.f; }
__device__ __forceinline__ u16 f2b(float x){ union{float f; u32 i;} t; t.f=x; u32 r=t.i+0x7FFFu+((t.i>>16)&1u); return (u16)(r>>16); }

__device__ __forceinline__ f32x4 mfma16(short8v a, short8v b, f32x4 c){
  return __builtin_amdgcn_mfma_f32_16x16x32_bf16(a, b, c, 0, 0, 0);
}

// ============ weight packing: fragment-ready bf16 2-term layouts ============
// conv: WCF[l][term][ks][t(32)][lane(64)][e(8)], value = term of Wm[k][h],
//   k = ks*32+(lane>>4)*8+e, n = t*16+(lane&15), m = n>>7, h = n&127
__global__ void k_pack_convw(const float* __restrict__ Wk, const float* __restrict__ Wq,
                             const float* __restrict__ Wv, const float* __restrict__ Ws,
                             u16* __restrict__ out){
  int idx = blockIdx.x*256 + threadIdx.x;
  if (idx >= 7*2*4*32*512) return;
  int e = idx & 7, lane = (idx>>3) & 63, t = (idx>>9) & 31;
  int ks = (idx>>14) & 3, term = (idx>>16) & 1, l = idx>>17;
  int k = ks*32 + (lane>>4)*8 + e;
  int n = t*16 + (lane & 15);
  int m = n>>7, h = n & 127;
  float val = 0.f;
  if (k < HH && h < HH){
    const float* W = (m==0)? Wk : (m==1)? Wq : (m==2)? Wv : Ws;
    val = W[l*9409 + k*97 + h];
  }
  u16 hi = f2b(val);
  out[idx] = (term==0)? hi : f2b(val - b2f(hi));
}

// gru: WGF[set(8)][mat(2)][term(2)][ks][t(24)][lane][e], cols packed j*128+g
__global__ void k_pack_gruw(const float* __restrict__ gih, const float* __restrict__ ghh,
                            const float* __restrict__ mih, const float* __restrict__ mhh,
                            u16* __restrict__ out){
  int idx = blockIdx.x*256 + threadIdx.x;
  if (idx >= 8*2*2*4*24*512) return;
  int e = idx & 7, lane = (idx>>3) & 63;
  int r1 = idx>>9;
  int t = r1 % 24, r2 = r1 / 24;
  int ks = r2 & 3, mt = (r2>>2) & 3, set = r2>>4;
  int mat = mt>>1, term = mt & 1;
  int k = ks*32 + (lane>>4)*8 + e;
  int n = t*16 + (lane & 15);
  int j = n>>7, g = n & 127;
  float val = 0.f;
  if (k < HH && g < HH){
    const float* src = (set < 7)? ((mat==0)? gih + (size_t)set*28227 : ghh + (size_t)set*28227)
                                : ((mat==0)? mih : mhh);
    val = src[k*291 + j*97 + g];
  }
  u16 hi = f2b(val);
  out[idx] = (term==0)? hi : f2b(val - b2f(hi));
}

// gat: GATF[term][ks][t(8)][lane][e]
__global__ void k_pack_gatw(const float* __restrict__ gatW, u16* __restrict__ out){
  int idx = blockIdx.x*256 + threadIdx.x;
  if (idx >= 2*4*8*512) return;
  int e = idx & 7, lane = (idx>>3) & 63, t = (idx>>9) & 7;
  int ks = (idx>>12) & 3, term = idx>>14;
  int k = ks*32 + (lane>>4)*8 + e;
  int h = t*16 + (lane & 15);
  float val = (k < HH && h < HH)? gatW[k*97 + h] : 0.f;
  u16 hi = f2b(val);
  out[idx] = (term==0)? hi : f2b(val - b2f(hi));
}

__global__ void k_pack_convb(const float* __restrict__ bk, const float* __restrict__ bq,
                             const float* __restrict__ bv, const float* __restrict__ bs,
                             float* __restrict__ out){
  int idx = blockIdx.x*256 + threadIdx.x;
  if (idx >= 7*512) return;
  int l = idx >> 9, c = idx & 511;
  int m = c >> 7, h = c & 127;
  float v = 0.f;
  if (h < HH){
    const float* B = (m==0)? bk : (m==1)? bq : (m==2)? bv : bs;
    v = B[l*97 + h];
  }
  out[idx] = v;
}

// gru biases gate-major: [set][j*128+g]
__global__ void k_pack_grub(const float* __restrict__ gbi, const float* __restrict__ gbh,
                            const float* __restrict__ mbi, const float* __restrict__ mbh,
                            float* __restrict__ obi, float* __restrict__ obh){
  int idx = blockIdx.x*256 + threadIdx.x;
  if (idx >= 8*384) return;
  int set = idx / 384, n = idx % 384;
  int j = n>>7, g = n & 127;
  float vi = 0.f, vh = 0.f;
  if (g < HH){
    const float* si = (set < 7)? gbi + set*291 : mbi;
    const float* sh = (set < 7)? gbh + set*291 : mbh;
    vi = si[j*97 + g];
    vh = sh[j*97 + g];
  }
  obi[idx] = vi; obh[idx] = vh;
}

// contiguous region: GATWP[16384] ASRCP[128] ADSTP[128] GBP[128] W2P[128] pad[512]
__global__ void k_pack_misc(const float* __restrict__ gatW, const float* __restrict__ asrc,
                            const float* __restrict__ adst, const float* __restrict__ gatb,
                            const float* __restrict__ l2W, float* __restrict__ out){
  int idx = blockIdx.x*256 + threadIdx.x;
  if (idx < 16384){
    int k = idx >> 7, h = idx & 127;
    out[idx] = (k < HH && h < HH)? gatW[k*97 + h] : 0.f;
  } else if (idx < 16512){
    int h = idx - 16384; out[idx] = (h < HH)? asrc[h] : 0.f;
  } else if (idx < 16640){
    int h = idx - 16512; out[idx] = (h < HH)? adst[h] : 0.f;
  } else if (idx < 16768){
    int h = idx - 16640; out[idx] = (h < HH)? gatb[h] : 0.f;
  } else if (idx < 16896){
    int h = idx - 16768; out[idx] = (h < HH)? l2W[h] : 0.f;
  } else if (idx < 17408){
    out[idx] = 0.f;
  }
}

// ============ graph preprocessing ============
__global__ void k_seg(const int* __restrict__ batch, int* __restrict__ seg){
  int g = blockIdx.x*blockDim.x + threadIdx.x;
  if (g > NG) return;
  int lo = 0, hi = NN;
  while (lo < hi){ int mid = (lo+hi) >> 1; if (batch[mid] < g) lo = mid+1; else hi = mid; }
  seg[g] = lo;
}

// ============ lin1 ============
__global__ __launch_bounds__(256) void k_lin1(const float* __restrict__ x,
    const float* __restrict__ W, const float* __restrict__ b, u16* __restrict__ X0){
  int idx = blockIdx.x*256 + threadIdx.x;
  int n = idx >> 7, c = idx & 127;
  float v = 0.f;
  if (c < HH){
    v = b[c];
    #pragma unroll
    for (int k = 0; k < 9; ++k) v += x[n*9 + k]*W[k*HH + c];
    v = lrelu01_(v);
  }
  X0[(size_t)n*HP + c] = f2b(v);
}

// ============ conv GEMM (MFMA): KQV bf16 + S fp32 = X @ Wconv + b ============
// grid M/32 blocks, 256 thr (4 waves). wave w covers cols [w*128, w*128+128) = slice w.
__global__ __launch_bounds__(256) void k_conv_mfma(const u16* __restrict__ X,
    const u16* __restrict__ WCF_l, const float* __restrict__ biasp,
    u16* __restrict__ KQV, float* __restrict__ S){
  int tid = threadIdx.x;
  int w = tid >> 6, lane = tid & 63;
  int lm = lane & 15, ls = lane >> 4;
  int m0 = blockIdx.x*32;
  f32x4 acc[2][8] = {};
  for (int ks = 0; ks < 4; ++ks){
    short8v aX[2];
    #pragma unroll
    for (int rb = 0; rb < 2; ++rb){
      int row = m0 + rb*16 + lm;
      aX[rb] = *(const short8v*)(X + (size_t)row*HP + ks*32 + ls*8);
    }
    #pragma unroll
    for (int t = 0; t < 8; ++t){
      int tg = w*8 + t;
      const u16* ph = WCF_l + (((size_t)(0*4 + ks)*32 + tg)*64 + lane)*8;
      const u16* pl = WCF_l + (((size_t)(1*4 + ks)*32 + tg)*64 + lane)*8;
      short8v bh = *(const short8v*)ph;
      short8v bl = *(const short8v*)pl;
      #pragma unroll
      for (int rb = 0; rb < 2; ++rb){
        acc[rb][t] = mfma16(aX[rb], bh, acc[rb][t]);
        acc[rb][t] = mfma16(aX[rb], bl, acc[rb][t]);
      }
    }
  }
  #pragma unroll
  for (int t = 0; t < 8; ++t){
    int c = t*16 + lm;               // col within slice
    float bv = biasp[w*128 + c];
    #pragma unroll
    for (int rb = 0; rb < 2; ++rb){
      #pragma unroll
      for (int r = 0; r < 4; ++r){
        int row = m0 + rb*16 + ls*4 + r;
        float v = acc[rb][t][r] + bv;
        if (w < 3) KQV[(size_t)row*384 + w*128 + c] = f2b(v);
        else       S[(size_t)row*HP + c] = v;
      }
    }
  }
}

// ============ GRU GEMM+gates (MFMA) ============
// Hin fp32 [M][128] (split 2-term in-reg), Xin bf16 [M][128].
// WGF_set: [mat2][term2][ks4][t24][512]; cols gate-major j*128+g.
// grid M/32, 4 waves; wave w owns base tiles {2w,2w+1} i.e. tiles {2w+b + 8j}.
__global__ __launch_bounds__(256) void k_gru_mfma(const float* __restrict__ Hin,
    const u16* __restrict__ Xin, const u16* __restrict__ WGF_set,
    const float* __restrict__ bihp, const float* __restrict__ bhhp,
    u16* __restrict__ Xout){
  int tid = threadIdx.x;
  int w = tid >> 6, lane = tid & 63;
  int lm = lane & 15, ls = lane >> 4;
  int m0 = blockIdx.x*32;
  f32x4 agi[2][2][3] = {};
  f32x4 agh[2][2][3] = {};
  for (int ks = 0; ks < 4; ++ks){
    short8v aX[2], aSh[2], aSl[2];
    #pragma unroll
    for (int rb = 0; rb < 2; ++rb){
      int row = m0 + rb*16 + lm;
      aX[rb] = *(const short8v*)(Xin + (size_t)row*HP + ks*32 + ls*8);
      const float* sp = Hin + (size_t)row*HP + ks*32 + ls*8;
      float sv[8];
      *(float4*)&sv[0] = *(const float4*)sp;
      *(float4*)&sv[4] = *(const float4*)(sp + 4);
      short8v vh, vl;
      #pragma unroll
      for (int e = 0; e < 8; ++e){
        u16 hb = f2b(sv[e]);
        vh[e] = (short)hb;
        vl[e] = (short)f2b(sv[e] - b2f(hb));
      }
      aSh[rb] = vh; aSl[rb] = vl;
    }
    #pragma unroll
    for (int b = 0; b < 2; ++b){
      #pragma unroll
      for (int j = 0; j < 3; ++j){
        int t = j*8 + 2*w + b;
        const u16* base = WGF_set;
        short8v bih_h = *(const short8v*)(base + (((size_t)(0*4 + ks)*24 + t)*64 + lane)*8);
        short8v bih_l = *(const short8v*)(base + (((size_t)(1*4 + ks)*24 + t)*64 + lane)*8);
        short8v bhh_h = *(const short8v*)(base + (((size_t)(2*4 + ks)*24 + t)*64 + lane)*8);
        short8v bhh_l = *(const short8v*)(base + (((size_t)(3*4 + ks)*24 + t)*64 + lane)*8);
        #pragma unroll
        for (int rb = 0; rb < 2; ++rb){
          agi[rb][b][j] = mfma16(aSh[rb], bih_h, agi[rb][b][j]);
          agi[rb][b][j] = mfma16(aSh[rb], bih_l, agi[rb][b][j]);
          agi[rb][b][j] = mfma16(aSl[rb], bih_h, agi[rb][b][j]);
          agh[rb][b][j] = mfma16(aX[rb], bhh_h, agh[rb][b][j]);
          agh[rb][b][j] = mfma16(aX[rb], bhh_l, agh[rb][b][j]);
        }
      }
    }
  }
  #pragma unroll
  for (int b = 0; b < 2; ++b){
    int g = (2*w + b)*16 + lm;
    float bi0 = bihp[g], bi1 = bihp[128+g], bi2 = bihp[256+g];
    float bh0 = bhhp[g], bh1 = bhhp[128+g], bh2 = bhhp[256+g];
    #pragma unroll
    for (int rb = 0; rb < 2; ++rb){
      #pragma unroll
      for (int r = 0; r < 4; ++r){
        int row = m0 + rb*16 + ls*4 + r;
        float ir = agi[rb][b][0][r] + bi0, iz = agi[rb][b][1][r] + bi1, in_ = agi[rb][b][2][r] + bi2;
        float hr = agh[rb][b][0][r] + bh0, hz = agh[rb][b][1][r] + bh1, hn = agh[rb][b][2][r] + bh2;
        float rr = sigm_(ir + hr);
        float zz = sigm_(iz + hz);
        float nn2 = tanh_(in_ + rr*hn);
        float xo = b2f(Xin[(size_t)row*HP + g]);
        float v = (1.f - zz)*nn2 + zz*xo;
        Xout[(size_t)row*HP + g] = f2b(fmaxf(v, 0.f));
      }
    }
  }
}

// ============ plain 128-col GEMM (MFMA): XS = X @ gatW ============
// grid M/32; wave w owns tiles {2w, 2w+1}
__global__ __launch_bounds__(256) void k_xs_mfma(const u16* __restrict__ X,
    const u16* __restrict__ GATF, u16* __restrict__ XS){
  int tid = threadIdx.x;
  int w = tid >> 6, lane = tid & 63;
  int lm = lane & 15, ls = lane >> 4;
  int m0 = blockIdx.x*32;
  f32x4 acc[2][2] = {};
  for (int ks = 0; ks < 4; ++ks){
    short8v aX[2];
    #pragma unroll
    for (int rb = 0; rb < 2; ++rb){
      int row = m0 + rb*16 + lm;
      aX[rb] = *(const short8v*)(X + (size_t)row*HP + ks*32 + ls*8);
    }
    #pragma unroll
    for (int b = 0; b < 2; ++b){
      int t = 2*w + b;
      short8v bh = *(const short8v*)(GATF + (((size_t)(0*4 + ks)*8 + t)*64 + lane)*8);
      short8v bl = *(const short8v*)(GATF + (((size_t)(1*4 + ks)*8 + t)*64 + lane)*8);
      #pragma unroll
      for (int rb = 0; rb < 2; ++rb){
        acc[rb][b] = mfma16(aX[rb], bh, acc[rb][b]);
        acc[rb][b] = mfma16(aX[rb], bl, acc[rb][b]);
      }
    }
  }
  #pragma unroll
  for (int b = 0; b < 2; ++b){
    int c = (2*w + b)*16 + lm;
    #pragma unroll
    for (int rb = 0; rb < 2; ++rb){
      #pragma unroll
      for (int r = 0; r < 4; ++r){
        int row = m0 + rb*16 + ls*4 + r;
        XS[(size_t)row*HP + c] = f2b(acc[rb][b][r]);
      }
    }
  }
}

// ============ edge message + fp32 atomic scatter (2 channels/thread) ============
__global__ __launch_bounds__(256) void k_edge(const u16* __restrict__ kqv,
    float* __restrict__ S, const int* __restrict__ src, const int* __restrict__ dst){
  int t = blockIdx.x*256 + threadIdx.x;
  int e = t >> 6, c2 = (t & 63)*2;
  if (c2 >= HH) return;
  int s = src[e], d = dst[e];
  const u16* kb = kqv + (size_t)d*384;
  const u16* qb = kqv + (size_t)s*384 + 128;
  const u16* vb = kqv + (size_t)s*384 + 256;
  ushort2 kk = *(const ushort2*)(kb + c2);
  ushort2 qq = *(const ushort2*)(qb + c2);
  ushort2 vv = *(const ushort2*)(vb + c2);
  float m0 = b2f(vv.x) * sigm_(b2f(kk.x) + b2f(qq.x));
  float m1 = b2f(vv.y) * sigm_(b2f(kk.y) + b2f(qq.y));
  float* sp = S + (size_t)d*HP + c2;
  atomicAdd(sp, m0);
  atomicAdd(sp + 1, m1);
}

// ============ elu (+ optional BN) in-place on S ============
__global__ __launch_bounds__(256) void k_elubn(float* __restrict__ S,
    const float* __restrict__ gamma, const float* __restrict__ beta,
    const float* __restrict__ mean, const float* __restrict__ var, int layer){
  int idx = blockIdx.x*256 + threadIdx.x;
  int n = idx >> 7, c = idx & 127;
  if (c >= HH) return;
  float* p = S + (size_t)n*HP + c;
  float v = *p;
  v = v > 0.f ? v : (__expf(v) - 1.f);
  if (layer > 0){
    int b = (layer-1)*97 + c;
    float sc = gamma[b]*rsqrtf(var[b] + 1e-5f);
    v = (v - mean[b])*sc + beta[b];
  }
  *p = v;
}

// ============ readout ============
__global__ __launch_bounds__(128) void k_pool(const int* __restrict__ seg,
    const u16* __restrict__ x, u16* __restrict__ out){
  int g = blockIdx.x, tid = threadIdx.x;
  int lo = seg[g], hi = seg[g+1];
  float acc = 0.f;
  for (int n = lo; n < hi; ++n) acc += b2f(x[(size_t)n*HP + tid]);
  out[(size_t)g*HP + tid] = f2b(fmaxf(acc, 0.f));
}

__global__ __launch_bounds__(256) void k_as(const u16* __restrict__ xs,
    const float* __restrict__ asrcp, float* __restrict__ a_s){
  int t = blockIdx.x*256 + threadIdx.x;
  int n = t >> 6, lane = t & 63;
  float v = b2f(xs[(size_t)n*HP + lane])*asrcp[lane]
          + b2f(xs[(size_t)n*HP + 64 + lane])*asrcp[64 + lane];
  #pragma unroll
  for (int o = 32; o > 0; o >>= 1) v += __shfl_down(v, o);
  if (lane == 0) a_s[n] = v;
}

__global__ __launch_bounds__(128) void k_ad(const u16* __restrict__ out,
    const float* __restrict__ gatwp, const float* __restrict__ adstp, float* __restrict__ ad){
  int g = blockIdx.x, tid = threadIdx.x;
  __shared__ float so[HP];
  __shared__ float red[2];
  so[tid] = b2f(out[(size_t)g*HP + tid]);
  __syncthreads();
  float p = 0.f;
  #pragma unroll 4
  for (int k = 0; k < HP; ++k) p += so[k]*gatwp[k*HP + tid];
  float v = p * adstp[tid];
  #pragma unroll
  for (int o = 32; o > 0; o >>= 1) v += __shfl_down(v, o);
  if ((tid & 63) == 0) red[tid >> 6] = v;
  __syncthreads();
  if (tid == 0) ad[g] = red[0] + red[1];
}

#define ACAP 2048
__global__ __launch_bounds__(128) void k_attn(const int* __restrict__ seg,
    const float* __restrict__ a_s, const float* __restrict__ a_d,
    const u16* __restrict__ xs, const float* __restrict__ gbp, float* __restrict__ hg){
  int g = blockIdx.x, tid = threadIdx.x;
  int lo = seg[g], hi = seg[g+1], cnt = hi - lo;
  float ad = a_d[g];
  __shared__ float sa[ACAP];
  __shared__ float red[2];
  float mloc = -3.4e38f;
  for (int i = tid; i < cnt; i += 128){
    float al = lrelu01_(a_s[lo+i] + ad);
    if (i < ACAP) sa[i] = al;
    mloc = fmaxf(mloc, al);
  }
  #pragma unroll
  for (int o = 32; o > 0; o >>= 1) mloc = fmaxf(mloc, __shfl_down(mloc, o));
  if ((tid & 63) == 0) red[tid >> 6] = mloc;
  __syncthreads();
  float mm = fmaxf(red[0], red[1]);
  __syncthreads();
  float sloc = 0.f;
  for (int i = tid; i < cnt; i += 128){
    float al = (i < ACAP)? sa[i] : lrelu01_(a_s[lo+i] + ad);
    float e = __expf(al - mm);
    if (i < ACAP) sa[i] = e;
    sloc += e;
  }
  #pragma unroll
  for (int o = 32; o > 0; o >>= 1) sloc += __shfl_down(sloc, o);
  if ((tid & 63) == 0) red[tid >> 6] = sloc;
  __syncthreads();
  float ss = red[0] + red[1];
  float inv = (cnt > 0 && ss != 0.f)? 1.f/ss : 0.f;
  __syncthreads();
  float accv = 0.f;
  for (int i = 0; i < cnt; ++i){
    float e = (i < ACAP)? sa[i] : __expf(lrelu01_(a_s[lo+i] + ad) - mm);
    accv += (e*inv) * b2f(xs[(size_t)(lo+i)*HP + tid]);
  }
  float hgv = accv + gbp[tid];
  hg[(size_t)g*HP + tid] = hgv > 0.f ? hgv : (__expf(hgv) - 1.f);
}

__global__ __launch_bounds__(64) void k_final(const u16* __restrict__ out,
    const float* __restrict__ w2p, const float* __restrict__ l2b, float* __restrict__ y){
  int g = blockIdx.x, lane = threadIdx.x;
  float v = b2f(out[(size_t)g*HP + lane])*w2p[lane]
          + b2f(out[(size_t)g*HP + 64 + lane])*w2p[64 + lane];
  #pragma unroll
  for (int o = 32; o > 0; o >>= 1) v += __shfl_down(v, o);
  if (lane == 0) y[g] = v + l2b[0];
}

// ============ host ============
extern "C" void kernel_launch(void* const* d_in, const int* in_sizes, int n_in,
                              void* d_out, int out_size, void* d_ws, size_t ws_size,
                              hipStream_t stream){
  const float* x_in  = (const float*)d_in[0];
  const int*   ei    = (const int*)d_in[1];
  const int*   batch = (const int*)d_in[2];
  const float* lin1W = (const float*)d_in[4];
  const float* lin1b = (const float*)d_in[5];
  const float* cWk = (const float*)d_in[6];
  const float* cWq = (const float*)d_in[7];
  const float* cWv = (const float*)d_in[8];
  const float* cWs = (const float*)d_in[9];
  const float* cbk = (const float*)d_in[10];
  const float* cbq = (const float*)d_in[11];
  const float* cbv = (const float*)d_in[12];
  const float* cbs = (const float*)d_in[13];
  const float* gWih = (const float*)d_in[14];
  const float* gWhh = (const float*)d_in[15];
  const float* gbih = (const float*)d_in[16];
  const float* gbhh = (const float*)d_in[17];
  const float* bng = (const float*)d_in[18];
  const float* bnb = (const float*)d_in[19];
  const float* bnm = (const float*)d_in[20];
  const float* bnv = (const float*)d_in[21];
  const float* gatW  = (const float*)d_in[22];
  const float* gasrc = (const float*)d_in[23];
  const float* gadst = (const float*)d_in[24];
  const float* gatb  = (const float*)d_in[25];
  const float* mWih = (const float*)d_in[26];
  const float* mWhh = (const float*)d_in[27];
  const float* mbih = (const float*)d_in[28];
  const float* mbhh = (const float*)d_in[29];
  const float* l2W = (const float*)d_in[30];
  const float* l2b = (const float*)d_in[31];
  const int* src = ei;
  const int* dst = ei + NE;

  char* base = (char*)d_ws;
  size_t off = 0;
  auto alloc = [&](size_t nbytes)->char*{
    char* p = base + off; off = (off + nbytes + 255) & ~(size_t)255; return p; };

  u16*  WCF  = (u16*)alloc((size_t)7*2*4*32*512*2);      // 1.8 MB
  u16*  WGF  = (u16*)alloc((size_t)8*2*2*4*24*512*2);    // 3.1 MB
  u16*  GATF = (u16*)alloc((size_t)2*4*8*512*2);         // 64 KB
  float* BCONVP = (float*)alloc(7*512*4);
  float* BIHP   = (float*)alloc(8*384*4);
  float* BHHP   = (float*)alloc(8*384*4);
  float* GATWP  = (float*)alloc(17408*4);
  float* ASRCP = GATWP + 16384;
  float* ADSTP = GATWP + 16512;
  float* GBP   = GATWP + 16640;
  float* W2P   = GATWP + 16768;
  u16*  X0  = (u16*)alloc((size_t)NN*HP*2);
  u16*  X1  = (u16*)alloc((size_t)NN*HP*2);
  u16*  KQV = (u16*)alloc((size_t)NN*384*2);
  float* S  = (float*)alloc((size_t)NN*HP*4);
  float* AS_ = (float*)alloc((size_t)NN*4);
  float* AD_ = (float*)alloc((size_t)NG*4);
  u16*  OUTA = (u16*)alloc((size_t)NG*HP*2);
  u16*  OUTB = (u16*)alloc((size_t)NG*HP*2);
  float* HG  = (float*)alloc((size_t)NG*HP*4);
  int*  SEG  = (int*)alloc((size_t)(NG+1)*4);

  if (ws_size < off){
    hipMemsetAsync(d_out, 0, (size_t)out_size*sizeof(float), stream);
    return;
  }

  k_pack_convw<<<(7*2*4*32*512+255)/256,256,0,stream>>>(cWk,cWq,cWv,cWs,WCF);
  k_pack_gruw<<<(8*2*2*4*24*512+255)/256,256,0,stream>>>(gWih,gWhh,mWih,mWhh,WGF);
  k_pack_gatw<<<(2*4*8*512+255)/256,256,0,stream>>>(gatW,GATF);
  k_pack_convb<<<(7*512+255)/256,256,0,stream>>>(cbk,cbq,cbv,cbs,BCONVP);
  k_pack_grub<<<(8*384+255)/256,256,0,stream>>>(gbih,gbhh,mbih,mbhh,BIHP,BHHP);
  k_pack_misc<<<68,256,0,stream>>>(gatW,gasrc,gadst,gatb,l2W,GATWP);
  k_lin1<<<(NN*HP)/256,256,0,stream>>>(x_in,lin1W,lin1b,X0);
  k_seg<<<(NG+1+255)/256,256,0,stream>>>(batch,SEG);

  for (int l = 0; l < 7; ++l){
    u16* Xin  = (l & 1)? X1 : X0;
    u16* Xout = (l & 1)? X0 : X1;
    k_conv_mfma<<<NN/32,256,0,stream>>>(Xin, WCF + (size_t)l*131072, BCONVP + l*512, KQV, S);
    k_edge<<<(NE*64)/256,256,0,stream>>>(KQV, S, src, dst);
    k_elubn<<<(NN*HP)/256,256,0,stream>>>(S, bng, bnb, bnm, bnv, l);
    k_gru_mfma<<<NN/32,256,0,stream>>>(S, Xin, WGF + (size_t)l*196608,
                                       BIHP + l*384, BHHP + l*384, Xout);
  }
  u16* XF = X1;  // after 7 layers (l=6 even: X0 -> X1)

  k_pool<<<NG,128,0,stream>>>(SEG, XF, OUTA);
  u16* XS = KQV;  // reuse as [NN][128] bf16
  k_xs_mfma<<<NN/32,256,0,stream>>>(XF, GATF, XS);
  k_as<<<(NN*64)/256,256,0,stream>>>(XS, ASRCP, AS_);

  u16* cur = OUTA; u16* nxt = OUTB;
  for (int s = 0; s < 7; ++s){
    k_ad<<<NG,128,0,stream>>>(cur, GATWP, ADSTP, AD_);
    k_attn<<<NG,128,0,stream>>>(SEG, AS_, AD_, XS, GBP, HG);
    k_gru_mfma<<<NG/32,256,0,stream>>>(HG, cur, WGF + (size_t)7*196608,
                                       BIHP + 7*384, BHHP + 7*384, nxt);
    u16* t = cur; cur = nxt; nxt = t;
  }
  k_final<<<NG,64,0,stream>>>(cur, W2P, l2b, (float*)d_out);
}

// Round 4
// 2808.042 us; speedup vs baseline: 4.8679x; 2.1651x over previous
//
#include <hip/hip_runtime.h>

#define NN 100000
#define NE 800000
#define NG 4096
#define HH 97
#define HP 128
#define NB 391   // (NN+255)/256 scan blocks

typedef unsigned short u16;
typedef unsigned int u32;
typedef __attribute__((ext_vector_type(8))) short short8v;
typedef __attribute__((ext_vector_type(4))) float f32x4;

__device__ __forceinline__ float sigm_(float x){ return 1.f/(1.f+__expf(-x)); }
__device__ __forceinline__ float lrelu01_(float x){ return x>0.f? x : 0.01f*x; }
__device__ __forceinline__ float tanh_(float t){ float e2=__expf(2.f*t); return 1.f-2.f/(e2+1.f); }
__device__ __forceinline__ float b2f(u16 u){ union{u32 i; float f;} t; t.i=(u32)u<<16; return t.f; }
__device__ __forceinline__ u16 f2b(float x){ union{float f; u32 i;} t; t.f=x; u32 r=t.i+0x7FFFu+((t.i>>16)&1u); return (u16)(r>>16); }

__device__ __forceinline__ f32x4 mfma16(short8v a, short8v b, f32x4 c){
  return __builtin_amdgcn_mfma_f32_16x16x32_bf16(a, b, c, 0, 0, 0);
}

// ============ weight packing: fragment-ready bf16 2-term layouts ============
__global__ void k_pack_convw(const float* __restrict__ Wk, const float* __restrict__ Wq,
                             const float* __restrict__ Wv, const float* __restrict__ Ws,
                             u16* __restrict__ out){
  int idx = blockIdx.x*256 + threadIdx.x;
  if (idx >= 7*2*4*32*512) return;
  int e = idx & 7, lane = (idx>>3) & 63, t = (idx>>9) & 31;
  int ks = (idx>>14) & 3, term = (idx>>16) & 1, l = idx>>17;
  int k = ks*32 + (lane>>4)*8 + e;
  int n = t*16 + (lane & 15);
  int m = n>>7, h = n & 127;
  float val = 0.f;
  if (k < HH && h < HH){
    const float* W = (m==0)? Wk : (m==1)? Wq : (m==2)? Wv : Ws;
    val = W[l*9409 + k*97 + h];
  }
  u16 hi = f2b(val);
  out[idx] = (term==0)? hi : f2b(val - b2f(hi));
}

__global__ void k_pack_gruw(const float* __restrict__ gih, const float* __restrict__ ghh,
                            const float* __restrict__ mih, const float* __restrict__ mhh,
                            u16* __restrict__ out){
  int idx = blockIdx.x*256 + threadIdx.x;
  if (idx >= 8*2*2*4*24*512) return;
  int e = idx & 7, lane = (idx>>3) & 63;
  int r1 = idx>>9;
  int t = r1 % 24, r2 = r1 / 24;
  int ks = r2 & 3, mt = (r2>>2) & 3, set = r2>>4;
  int mat = mt>>1, term = mt & 1;
  int k = ks*32 + (lane>>4)*8 + e;
  int n = t*16 + (lane & 15);
  int j = n>>7, g = n & 127;
  float val = 0.f;
  if (k < HH && g < HH){
    const float* src = (set < 7)? ((mat==0)? gih + (size_t)set*28227 : ghh + (size_t)set*28227)
                                : ((mat==0)? mih : mhh);
    val = src[k*291 + j*97 + g];
  }
  u16 hi = f2b(val);
  out[idx] = (term==0)? hi : f2b(val - b2f(hi));
}

__global__ void k_pack_gatw(const float* __restrict__ gatW, u16* __restrict__ out){
  int idx = blockIdx.x*256 + threadIdx.x;
  if (idx >= 2*4*8*512) return;
  int e = idx & 7, lane = (idx>>3) & 63, t = (idx>>9) & 7;
  int ks = (idx>>12) & 3, term = idx>>14;
  int k = ks*32 + (lane>>4)*8 + e;
  int h = t*16 + (lane & 15);
  float val = (k < HH && h < HH)? gatW[k*97 + h] : 0.f;
  u16 hi = f2b(val);
  out[idx] = (term==0)? hi : f2b(val - b2f(hi));
}

__global__ void k_pack_convb(const float* __restrict__ bk, const float* __restrict__ bq,
                             const float* __restrict__ bv, const float* __restrict__ bs,
                             float* __restrict__ out){
  int idx = blockIdx.x*256 + threadIdx.x;
  if (idx >= 7*512) return;
  int l = idx >> 9, c = idx & 511;
  int m = c >> 7, h = c & 127;
  float v = 0.f;
  if (h < HH){
    const float* B = (m==0)? bk : (m==1)? bq : (m==2)? bv : bs;
    v = B[l*97 + h];
  }
  out[idx] = v;
}

__global__ void k_pack_grub(const float* __restrict__ gbi, const float* __restrict__ gbh,
                            const float* __restrict__ mbi, const float* __restrict__ mbh,
                            float* __restrict__ obi, float* __restrict__ obh){
  int idx = blockIdx.x*256 + threadIdx.x;
  if (idx >= 8*384) return;
  int set = idx / 384, n = idx % 384;
  int j = n>>7, g = n & 127;
  float vi = 0.f, vh = 0.f;
  if (g < HH){
    const float* si = (set < 7)? gbi + set*291 : mbi;
    const float* sh = (set < 7)? gbh + set*291 : mbh;
    vi = si[j*97 + g];
    vh = sh[j*97 + g];
  }
  obi[idx] = vi; obh[idx] = vh;
}

// contiguous region: GATWP[16384] ASRCP[128] ADSTP[128] GBP[128] W2P[128] pad[512]
__global__ void k_pack_misc(const float* __restrict__ gatW, const float* __restrict__ asrc,
                            const float* __restrict__ adst, const float* __restrict__ gatb,
                            const float* __restrict__ l2W, float* __restrict__ out){
  int idx = blockIdx.x*256 + threadIdx.x;
  if (idx < 16384){
    int k = idx >> 7, h = idx & 127;
    out[idx] = (k < HH && h < HH)? gatW[k*97 + h] : 0.f;
  } else if (idx < 16512){
    int h = idx - 16384; out[idx] = (h < HH)? asrc[h] : 0.f;
  } else if (idx < 16640){
    int h = idx - 16512; out[idx] = (h < HH)? adst[h] : 0.f;
  } else if (idx < 16768){
    int h = idx - 16640; out[idx] = (h < HH)? gatb[h] : 0.f;
  } else if (idx < 16896){
    int h = idx - 16768; out[idx] = (h < HH)? l2W[h] : 0.f;
  } else if (idx < 17408){
    out[idx] = 0.f;
  }
}

// ============ graph preprocessing ============
__global__ void k_seg(const int* __restrict__ batch, int* __restrict__ seg){
  int g = blockIdx.x*blockDim.x + threadIdx.x;
  if (g > NG) return;
  int lo = 0, hi = NN;
  while (lo < hi){ int mid = (lo+hi) >> 1; if (batch[mid] < g) lo = mid+1; else hi = mid; }
  seg[g] = lo;
}

// ---- CSR build: histogram -> 3-phase exclusive scan -> scatter ----
__global__ void k_hist(const int* __restrict__ dst, int* __restrict__ cnt){
  int e = blockIdx.x*256 + threadIdx.x;
  if (e < NE) atomicAdd(&cnt[dst[e]], 1);
}

__global__ void k_scan_blk(const int* __restrict__ cnt, int* __restrict__ offs,
                           int* __restrict__ bsum){
  __shared__ int s[256];
  int b = blockIdx.x, t = threadIdx.x, i = b*256 + t;
  int v = (i < NN)? cnt[i] : 0;
  s[t] = v; __syncthreads();
  #pragma unroll
  for (int off = 1; off < 256; off <<= 1){
    int tmp = (t >= off)? s[t-off] : 0;
    __syncthreads();
    s[t] += tmp;
    __syncthreads();
  }
  if (i < NN) offs[i] = s[t] - v;          // block-local exclusive
  if (t == 255) bsum[b] = s[255];
}

__global__ void k_scan_top(int* __restrict__ bsum){
  __shared__ int s[512];
  int t = threadIdx.x;
  int v = (t < NB)? bsum[t] : 0;
  s[t] = v; __syncthreads();
  #pragma unroll
  for (int off = 1; off < 512; off <<= 1){
    int tmp = (t >= off)? s[t-off] : 0;
    __syncthreads();
    s[t] += tmp;
    __syncthreads();
  }
  if (t < NB) bsum[t] = s[t] - v;          // exclusive
}

__global__ void k_scan_add(int* __restrict__ offs, const int* __restrict__ bsum,
                           int* __restrict__ cur){
  int b = blockIdx.x, t = threadIdx.x, i = b*256 + t;
  if (i < NN){ int o = offs[i] + bsum[b]; offs[i] = o; cur[i] = o; }
  if (i == 0) offs[NN] = NE;
}

__global__ void k_scatter(const int* __restrict__ src, const int* __restrict__ dst,
                          int* __restrict__ cur, int* __restrict__ eidx){
  int e = blockIdx.x*256 + threadIdx.x;
  if (e >= NE) return;
  int pos = atomicAdd(&cur[dst[e]], 1);
  eidx[pos] = src[e];
}

// ============ lin1 ============
__global__ __launch_bounds__(256) void k_lin1(const float* __restrict__ x,
    const float* __restrict__ W, const float* __restrict__ b, u16* __restrict__ X0){
  int idx = blockIdx.x*256 + threadIdx.x;
  int n = idx >> 7, c = idx & 127;
  float v = 0.f;
  if (c < HH){
    v = b[c];
    #pragma unroll
    for (int k = 0; k < 9; ++k) v += x[n*9 + k]*W[k*HH + c];
    v = lrelu01_(v);
  }
  X0[(size_t)n*HP + c] = f2b(v);
}

// ============ conv GEMM (MFMA): KQV bf16 + S fp32 = X @ Wconv + b ============
__global__ __launch_bounds__(256) void k_conv_mfma(const u16* __restrict__ X,
    const u16* __restrict__ WCF_l, const float* __restrict__ biasp,
    u16* __restrict__ KQV, float* __restrict__ S){
  int tid = threadIdx.x;
  int w = tid >> 6, lane = tid & 63;
  int lm = lane & 15, ls = lane >> 4;
  int m0 = blockIdx.x*32;
  f32x4 acc[2][8] = {};
  for (int ks = 0; ks < 4; ++ks){
    short8v aX[2];
    #pragma unroll
    for (int rb = 0; rb < 2; ++rb){
      int row = m0 + rb*16 + lm;
      aX[rb] = *(const short8v*)(X + (size_t)row*HP + ks*32 + ls*8);
    }
    #pragma unroll
    for (int t = 0; t < 8; ++t){
      int tg = w*8 + t;
      const u16* ph = WCF_l + (((size_t)(0*4 + ks)*32 + tg)*64 + lane)*8;
      const u16* pl = WCF_l + (((size_t)(1*4 + ks)*32 + tg)*64 + lane)*8;
      short8v bh = *(const short8v*)ph;
      short8v bl = *(const short8v*)pl;
      #pragma unroll
      for (int rb = 0; rb < 2; ++rb){
        acc[rb][t] = mfma16(aX[rb], bh, acc[rb][t]);
        acc[rb][t] = mfma16(aX[rb], bl, acc[rb][t]);
      }
    }
  }
  #pragma unroll
  for (int t = 0; t < 8; ++t){
    int c = t*16 + lm;
    float bv = biasp[w*128 + c];
    #pragma unroll
    for (int rb = 0; rb < 2; ++rb){
      #pragma unroll
      for (int r = 0; r < 4; ++r){
        int row = m0 + rb*16 + ls*4 + r;
        float v = acc[rb][t][r] + bv;
        if (w < 3) KQV[(size_t)row*384 + w*128 + c] = f2b(v);
        else       S[(size_t)row*HP + c] = v;
      }
    }
  }
}

// ============ GRU GEMM+gates (MFMA) ============
__global__ __launch_bounds__(256) void k_gru_mfma(const float* __restrict__ Hin,
    const u16* __restrict__ Xin, const u16* __restrict__ WGF_set,
    const float* __restrict__ bihp, const float* __restrict__ bhhp,
    u16* __restrict__ Xout){
  int tid = threadIdx.x;
  int w = tid >> 6, lane = tid & 63;
  int lm = lane & 15, ls = lane >> 4;
  int m0 = blockIdx.x*32;
  f32x4 agi[2][2][3] = {};
  f32x4 agh[2][2][3] = {};
  for (int ks = 0; ks < 4; ++ks){
    short8v aX[2], aSh[2], aSl[2];
    #pragma unroll
    for (int rb = 0; rb < 2; ++rb){
      int row = m0 + rb*16 + lm;
      aX[rb] = *(const short8v*)(Xin + (size_t)row*HP + ks*32 + ls*8);
      const float* sp = Hin + (size_t)row*HP + ks*32 + ls*8;
      float sv[8];
      *(float4*)&sv[0] = *(const float4*)sp;
      *(float4*)&sv[4] = *(const float4*)(sp + 4);
      short8v vh, vl;
      #pragma unroll
      for (int e = 0; e < 8; ++e){
        u16 hb = f2b(sv[e]);
        vh[e] = (short)hb;
        vl[e] = (short)f2b(sv[e] - b2f(hb));
      }
      aSh[rb] = vh; aSl[rb] = vl;
    }
    #pragma unroll
    for (int b = 0; b < 2; ++b){
      #pragma unroll
      for (int j = 0; j < 3; ++j){
        int t = j*8 + 2*w + b;
        const u16* base = WGF_set;
        short8v bih_h = *(const short8v*)(base + (((size_t)(0*4 + ks)*24 + t)*64 + lane)*8);
        short8v bih_l = *(const short8v*)(base + (((size_t)(1*4 + ks)*24 + t)*64 + lane)*8);
        short8v bhh_h = *(const short8v*)(base + (((size_t)(2*4 + ks)*24 + t)*64 + lane)*8);
        short8v bhh_l = *(const short8v*)(base + (((size_t)(3*4 + ks)*24 + t)*64 + lane)*8);
        #pragma unroll
        for (int rb = 0; rb < 2; ++rb){
          agi[rb][b][j] = mfma16(aSh[rb], bih_h, agi[rb][b][j]);
          agi[rb][b][j] = mfma16(aSh[rb], bih_l, agi[rb][b][j]);
          agi[rb][b][j] = mfma16(aSl[rb], bih_h, agi[rb][b][j]);
          agh[rb][b][j] = mfma16(aX[rb], bhh_h, agh[rb][b][j]);
          agh[rb][b][j] = mfma16(aX[rb], bhh_l, agh[rb][b][j]);
        }
      }
    }
  }
  #pragma unroll
  for (int b = 0; b < 2; ++b){
    int g = (2*w + b)*16 + lm;
    float bi0 = bihp[g], bi1 = bihp[128+g], bi2 = bihp[256+g];
    float bh0 = bhhp[g], bh1 = bhhp[128+g], bh2 = bhhp[256+g];
    #pragma unroll
    for (int rb = 0; rb < 2; ++rb){
      #pragma unroll
      for (int r = 0; r < 4; ++r){
        int row = m0 + rb*16 + ls*4 + r;
        float ir = agi[rb][b][0][r] + bi0, iz = agi[rb][b][1][r] + bi1, in_ = agi[rb][b][2][r] + bi2;
        float hr = agh[rb][b][0][r] + bh0, hz = agh[rb][b][1][r] + bh1, hn = agh[rb][b][2][r] + bh2;
        float rr = sigm_(ir + hr);
        float zz = sigm_(iz + hz);
        float nn2 = tanh_(in_ + rr*hn);
        float xo = b2f(Xin[(size_t)row*HP + g]);
        float v = (1.f - zz)*nn2 + zz*xo;
        Xout[(size_t)row*HP + g] = f2b(fmaxf(v, 0.f));
      }
    }
  }
}

// ============ plain 128-col GEMM (MFMA): XS = X @ gatW ============
__global__ __launch_bounds__(256) void k_xs_mfma(const u16* __restrict__ X,
    const u16* __restrict__ GATF, u16* __restrict__ XS){
  int tid = threadIdx.x;
  int w = tid >> 6, lane = tid & 63;
  int lm = lane & 15, ls = lane >> 4;
  int m0 = blockIdx.x*32;
  f32x4 acc[2][2] = {};
  for (int ks = 0; ks < 4; ++ks){
    short8v aX[2];
    #pragma unroll
    for (int rb = 0; rb < 2; ++rb){
      int row = m0 + rb*16 + lm;
      aX[rb] = *(const short8v*)(X + (size_t)row*HP + ks*32 + ls*8);
    }
    #pragma unroll
    for (int b = 0; b < 2; ++b){
      int t = 2*w + b;
      short8v bh = *(const short8v*)(GATF + (((size_t)(0*4 + ks)*8 + t)*64 + lane)*8);
      short8v bl = *(const short8v*)(GATF + (((size_t)(1*4 + ks)*8 + t)*64 + lane)*8);
      #pragma unroll
      for (int rb = 0; rb < 2; ++rb){
        acc[rb][b] = mfma16(aX[rb], bh, acc[rb][b]);
        acc[rb][b] = mfma16(aX[rb], bl, acc[rb][b]);
      }
    }
  }
  #pragma unroll
  for (int b = 0; b < 2; ++b){
    int c = (2*w + b)*16 + lm;
    #pragma unroll
    for (int rb = 0; rb < 2; ++rb){
      #pragma unroll
      for (int r = 0; r < 4; ++r){
        int row = m0 + rb*16 + ls*4 + r;
        XS[(size_t)row*HP + c] = f2b(acc[rb][b][r]);
      }
    }
  }
}

// ============ CSR aggregation + residual + ELU + BN, one wave per dst node ============
__global__ __launch_bounds__(256) void k_agg(const u16* __restrict__ kqv,
    const int* __restrict__ offs, const int* __restrict__ eidx,
    float* __restrict__ S, const float* __restrict__ gamma, const float* __restrict__ beta,
    const float* __restrict__ mean, const float* __restrict__ var, int layer){
  int n = blockIdx.x*4 + (threadIdx.x >> 6);
  if (n >= NN) return;
  int lane = threadIdx.x & 63;
  int c2 = lane*2;
  int lo = offs[n], hi = offs[n+1];
  ushort2 kk = *(const ushort2*)(kqv + (size_t)n*384 + c2);
  float k0 = b2f(kk.x), k1 = b2f(kk.y);
  float a0 = 0.f, a1 = 0.f;
  for (int i = lo; i < hi; ++i){
    int s = eidx[i];
    const u16* qb = kqv + (size_t)s*384 + 128 + c2;
    ushort2 qq = *(const ushort2*)qb;
    ushort2 vv = *(const ushort2*)(qb + 128);
    a0 += b2f(vv.x)*sigm_(k0 + b2f(qq.x));
    a1 += b2f(vv.y)*sigm_(k1 + b2f(qq.y));
  }
  float* sp = S + (size_t)n*HP + c2;
  float2 sr = *(float2*)sp;
  float v0 = sr.x + a0, v1 = sr.y + a1;
  v0 = v0 > 0.f ? v0 : (__expf(v0) - 1.f);
  v1 = v1 > 0.f ? v1 : (__expf(v1) - 1.f);
  if (layer > 0){
    int b0 = (layer-1)*97 + c2;
    if (c2 < HH){ float sc = gamma[b0]*rsqrtf(var[b0] + 1e-5f); v0 = (v0 - mean[b0])*sc + beta[b0]; }
    if (c2+1 < HH){ float sc = gamma[b0+1]*rsqrtf(var[b0+1] + 1e-5f); v1 = (v1 - mean[b0+1])*sc + beta[b0+1]; }
  }
  if (c2 >= HH)   v0 = 0.f;
  if (c2+1 >= HH) v1 = 0.f;
  *(float2*)sp = make_float2(v0, v1);
}

// ============ readout ============
__global__ __launch_bounds__(128) void k_pool(const int* __restrict__ seg,
    const u16* __restrict__ x, u16* __restrict__ out){
  int g = blockIdx.x, tid = threadIdx.x;
  int lo = seg[g], hi = seg[g+1];
  float acc = 0.f;
  for (int n = lo; n < hi; ++n) acc += b2f(x[(size_t)n*HP + tid]);
  out[(size_t)g*HP + tid] = f2b(fmaxf(acc, 0.f));
}

__global__ __launch_bounds__(256) void k_as(const u16* __restrict__ xs,
    const float* __restrict__ asrcp, float* __restrict__ a_s){
  int t = blockIdx.x*256 + threadIdx.x;
  int n = t >> 6, lane = t & 63;
  float v = b2f(xs[(size_t)n*HP + lane])*asrcp[lane]
          + b2f(xs[(size_t)n*HP + 64 + lane])*asrcp[64 + lane];
  #pragma unroll
  for (int o = 32; o > 0; o >>= 1) v += __shfl_down(v, o);
  if (lane == 0) a_s[n] = v;
}

__global__ __launch_bounds__(128) void k_ad(const u16* __restrict__ out,
    const float* __restrict__ gatwp, const float* __restrict__ adstp, float* __restrict__ ad){
  int g = blockIdx.x, tid = threadIdx.x;
  __shared__ float so[HP];
  __shared__ float red[2];
  so[tid] = b2f(out[(size_t)g*HP + tid]);
  __syncthreads();
  float p = 0.f;
  #pragma unroll 4
  for (int k = 0; k < HP; ++k) p += so[k]*gatwp[k*HP + tid];
  float v = p * adstp[tid];
  #pragma unroll
  for (int o = 32; o > 0; o >>= 1) v += __shfl_down(v, o);
  if ((tid & 63) == 0) red[tid >> 6] = v;
  __syncthreads();
  if (tid == 0) ad[g] = red[0] + red[1];
}

#define ACAP 2048
__global__ __launch_bounds__(128) void k_attn(const int* __restrict__ seg,
    const float* __restrict__ a_s, const float* __restrict__ a_d,
    const u16* __restrict__ xs, const float* __restrict__ gbp, float* __restrict__ hg){
  int g = blockIdx.x, tid = threadIdx.x;
  int lo = seg[g], hi = seg[g+1], cnt = hi - lo;
  float ad = a_d[g];
  __shared__ float sa[ACAP];
  __shared__ float red[2];
  float mloc = -3.4e38f;
  for (int i = tid; i < cnt; i += 128){
    float al = lrelu01_(a_s[lo+i] + ad);
    if (i < ACAP) sa[i] = al;
    mloc = fmaxf(mloc, al);
  }
  #pragma unroll
  for (int o = 32; o > 0; o >>= 1) mloc = fmaxf(mloc, __shfl_down(mloc, o));
  if ((tid & 63) == 0) red[tid >> 6] = mloc;
  __syncthreads();
  float mm = fmaxf(red[0], red[1]);
  __syncthreads();
  float sloc = 0.f;
  for (int i = tid; i < cnt; i += 128){
    float al = (i < ACAP)? sa[i] : lrelu01_(a_s[lo+i] + ad);
    float e = __expf(al - mm);
    if (i < ACAP) sa[i] = e;
    sloc += e;
  }
  #pragma unroll
  for (int o = 32; o > 0; o >>= 1) sloc += __shfl_down(sloc, o);
  if ((tid & 63) == 0) red[tid >> 6] = sloc;
  __syncthreads();
  float ss = red[0] + red[1];
  float inv = (cnt > 0 && ss != 0.f)? 1.f/ss : 0.f;
  __syncthreads();
  float accv = 0.f;
  for (int i = 0; i < cnt; ++i){
    float e = (i < ACAP)? sa[i] : __expf(lrelu01_(a_s[lo+i] + ad) - mm);
    accv += (e*inv) * b2f(xs[(size_t)(lo+i)*HP + tid]);
  }
  float hgv = accv + gbp[tid];
  hg[(size_t)g*HP + tid] = hgv > 0.f ? hgv : (__expf(hgv) - 1.f);
}

__global__ __launch_bounds__(64) void k_final(const u16* __restrict__ out,
    const float* __restrict__ w2p, const float* __restrict__ l2b, float* __restrict__ y){
  int g = blockIdx.x, lane = threadIdx.x;
  float v = b2f(out[(size_t)g*HP + lane])*w2p[lane]
          + b2f(out[(size_t)g*HP + 64 + lane])*w2p[64 + lane];
  #pragma unroll
  for (int o = 32; o > 0; o >>= 1) v += __shfl_down(v, o);
  if (lane == 0) y[g] = v + l2b[0];
}

// ============ host ============
extern "C" void kernel_launch(void* const* d_in, const int* in_sizes, int n_in,
                              void* d_out, int out_size, void* d_ws, size_t ws_size,
                              hipStream_t stream){
  const float* x_in  = (const float*)d_in[0];
  const int*   ei    = (const int*)d_in[1];
  const int*   batch = (const int*)d_in[2];
  const float* lin1W = (const float*)d_in[4];
  const float* lin1b = (const float*)d_in[5];
  const float* cWk = (const float*)d_in[6];
  const float* cWq = (const float*)d_in[7];
  const float* cWv = (const float*)d_in[8];
  const float* cWs = (const float*)d_in[9];
  const float* cbk = (const float*)d_in[10];
  const float* cbq = (const float*)d_in[11];
  const float* cbv = (const float*)d_in[12];
  const float* cbs = (const float*)d_in[13];
  const float* gWih = (const float*)d_in[14];
  const float* gWhh = (const float*)d_in[15];
  const float* gbih = (const float*)d_in[16];
  const float* gbhh = (const float*)d_in[17];
  const float* bng = (const float*)d_in[18];
  const float* bnb = (const float*)d_in[19];
  const float* bnm = (const float*)d_in[20];
  const float* bnv = (const float*)d_in[21];
  const float* gatW  = (const float*)d_in[22];
  const float* gasrc = (const float*)d_in[23];
  const float* gadst = (const float*)d_in[24];
  const float* gatb  = (const float*)d_in[25];
  const float* mWih = (const float*)d_in[26];
  const float* mWhh = (const float*)d_in[27];
  const float* mbih = (const float*)d_in[28];
  const float* mbhh = (const float*)d_in[29];
  const float* l2W = (const float*)d_in[30];
  const float* l2b = (const float*)d_in[31];
  const int* src = ei;
  const int* dst = ei + NE;

  char* base = (char*)d_ws;
  size_t off = 0;
  auto alloc = [&](size_t nbytes)->char*{
    char* p = base + off; off = (off + nbytes + 255) & ~(size_t)255; return p; };

  u16*  WCF  = (u16*)alloc((size_t)7*2*4*32*512*2);
  u16*  WGF  = (u16*)alloc((size_t)8*2*2*4*24*512*2);
  u16*  GATF = (u16*)alloc((size_t)2*4*8*512*2);
  float* BCONVP = (float*)alloc(7*512*4);
  float* BIHP   = (float*)alloc(8*384*4);
  float* BHHP   = (float*)alloc(8*384*4);
  float* GATWP  = (float*)alloc(17408*4);
  float* ASRCP = GATWP + 16384;
  float* ADSTP = GATWP + 16512;
  float* GBP   = GATWP + 16640;
  float* W2P   = GATWP + 16768;
  u16*  X0  = (u16*)alloc((size_t)NN*HP*2);
  u16*  X1  = (u16*)alloc((size_t)NN*HP*2);
  u16*  KQV = (u16*)alloc((size_t)NN*384*2);
  float* S  = (float*)alloc((size_t)NN*HP*4);
  float* AS_ = (float*)alloc((size_t)NN*4);
  float* AD_ = (float*)alloc((size_t)NG*4);
  u16*  OUTA = (u16*)alloc((size_t)NG*HP*2);
  u16*  OUTB = (u16*)alloc((size_t)NG*HP*2);
  float* HG  = (float*)alloc((size_t)NG*HP*4);
  int*  SEG  = (int*)alloc((size_t)(NG+1)*4);
  int*  CNT  = (int*)alloc((size_t)NN*4);
  int*  OFFS = (int*)alloc((size_t)(NN+1)*4);
  int*  CUR  = (int*)alloc((size_t)NN*4);
  int*  EIDX = (int*)alloc((size_t)NE*4);
  int*  BSUM = (int*)alloc((size_t)NB*4);

  if (ws_size < off){
    hipMemsetAsync(d_out, 0, (size_t)out_size*sizeof(float), stream);
    return;
  }

  // ---- one-time packing + graph prep ----
  k_pack_convw<<<(7*2*4*32*512+255)/256,256,0,stream>>>(cWk,cWq,cWv,cWs,WCF);
  k_pack_gruw<<<(8*2*2*4*24*512+255)/256,256,0,stream>>>(gWih,gWhh,mWih,mWhh,WGF);
  k_pack_gatw<<<(2*4*8*512+255)/256,256,0,stream>>>(gatW,GATF);
  k_pack_convb<<<(7*512+255)/256,256,0,stream>>>(cbk,cbq,cbv,cbs,BCONVP);
  k_pack_grub<<<(8*384+255)/256,256,0,stream>>>(gbih,gbhh,mbih,mbhh,BIHP,BHHP);
  k_pack_misc<<<68,256,0,stream>>>(gatW,gasrc,gadst,gatb,l2W,GATWP);
  k_lin1<<<(NN*HP)/256,256,0,stream>>>(x_in,lin1W,lin1b,X0);
  k_seg<<<(NG+1+255)/256,256,0,stream>>>(batch,SEG);

  hipMemsetAsync(CNT, 0, (size_t)NN*4, stream);
  k_hist<<<(NE+255)/256,256,0,stream>>>(dst, CNT);
  k_scan_blk<<<NB,256,0,stream>>>(CNT, OFFS, BSUM);
  k_scan_top<<<1,512,0,stream>>>(BSUM);
  k_scan_add<<<NB,256,0,stream>>>(OFFS, BSUM, CUR);
  k_scatter<<<(NE+255)/256,256,0,stream>>>(src, dst, CUR, EIDX);

  // ---- 7 conv+gru layers ----
  for (int l = 0; l < 7; ++l){
    u16* Xin  = (l & 1)? X1 : X0;
    u16* Xout = (l & 1)? X0 : X1;
    k_conv_mfma<<<NN/32,256,0,stream>>>(Xin, WCF + (size_t)l*131072, BCONVP + l*512, KQV, S);
    k_agg<<<(NN+3)/4,256,0,stream>>>(KQV, OFFS, EIDX, S, bng, bnb, bnm, bnv, l);
    k_gru_mfma<<<NN/32,256,0,stream>>>(S, Xin, WGF + (size_t)l*196608,
                                       BIHP + l*384, BHHP + l*384, Xout);
  }
  u16* XF = X1;

  // ---- readout ----
  k_pool<<<NG,128,0,stream>>>(SEG, XF, OUTA);
  u16* XS = KQV;
  k_xs_mfma<<<NN/32,256,0,stream>>>(XF, GATF, XS);
  k_as<<<(NN*64)/256,256,0,stream>>>(XS, ASRCP, AS_);

  u16* cur = OUTA; u16* nxt = OUTB;
  for (int s = 0; s < 7; ++s){
    k_ad<<<NG,128,0,stream>>>(cur, GATWP, ADSTP, AD_);
    k_attn<<<NG,128,0,stream>>>(SEG, AS_, AD_, XS, GBP, HG);
    k_gru_mfma<<<NG/32,256,0,stream>>>(HG, cur, WGF + (size_t)7*196608,
                                       BIHP + 7*384, BHHP + 7*384, nxt);
    u16* t = cur; cur = nxt; nxt = t;
  }
  k_final<<<NG,64,0,stream>>>(cur, W2P, l2b, (float*)d_out);
}

// Round 5
// 2447.095 us; speedup vs baseline: 5.5859x; 1.1475x over previous
//
#include <hip/hip_runtime.h>

#define NN 100000
#define NNP 100032   // padded to 64-row multiple
#define NE 800000
#define NG 4096
#define HH 97
#define HP 128
#define NB 391   // (NN+255)/256 scan blocks

typedef unsigned short u16;
typedef unsigned int u32;
typedef __attribute__((ext_vector_type(8))) short short8v;
typedef __attribute__((ext_vector_type(4))) float f32x4;

__device__ __forceinline__ float sigm_(float x){ return 1.f/(1.f+__expf(-x)); }
__device__ __forceinline__ float lrelu01_(float x){ return x>0.f? x : 0.01f*x; }
__device__ __forceinline__ float tanh_(float t){ float e2=__expf(2.f*t); return 1.f-2.f/(e2+1.f); }
__device__ __forceinline__ float b2f(u16 u){ union{u32 i; float f;} t; t.i=(u32)u<<16; return t.f; }
__device__ __forceinline__ u16 f2b(float x){ union{float f; u32 i;} t; t.f=x; u32 r=t.i+0x7FFFu+((t.i>>16)&1u); return (u16)(r>>16); }

__device__ __forceinline__ f32x4 mfma16(short8v a, short8v b, f32x4 c){
  return __builtin_amdgcn_mfma_f32_16x16x32_bf16(a, b, c, 0, 0, 0);
}

// ============ weight packing: fragment-ready bf16 2-term layouts ============
__global__ void k_pack_convw(const float* __restrict__ Wk, const float* __restrict__ Wq,
                             const float* __restrict__ Wv, const float* __restrict__ Ws,
                             u16* __restrict__ out){
  int idx = blockIdx.x*256 + threadIdx.x;
  if (idx >= 7*2*4*32*512) return;
  int e = idx & 7, lane = (idx>>3) & 63, t = (idx>>9) & 31;
  int ks = (idx>>14) & 3, term = (idx>>16) & 1, l = idx>>17;
  int k = ks*32 + (lane>>4)*8 + e;
  int n = t*16 + (lane & 15);
  int m = n>>7, h = n & 127;
  float val = 0.f;
  if (k < HH && h < HH){
    const float* W = (m==0)? Wk : (m==1)? Wq : (m==2)? Wv : Ws;
    val = W[l*9409 + k*97 + h];
  }
  u16 hi = f2b(val);
  out[idx] = (term==0)? hi : f2b(val - b2f(hi));
}

__global__ void k_pack_gruw(const float* __restrict__ gih, const float* __restrict__ ghh,
                            const float* __restrict__ mih, const float* __restrict__ mhh,
                            u16* __restrict__ out){
  int idx = blockIdx.x*256 + threadIdx.x;
  if (idx >= 8*2*2*4*24*512) return;
  int e = idx & 7, lane = (idx>>3) & 63;
  int r1 = idx>>9;
  int t = r1 % 24, r2 = r1 / 24;
  int ks = r2 & 3, mt = (r2>>2) & 3, set = r2>>4;
  int mat = mt>>1, term = mt & 1;
  int k = ks*32 + (lane>>4)*8 + e;
  int n = t*16 + (lane & 15);
  int j = n>>7, g = n & 127;
  float val = 0.f;
  if (k < HH && g < HH){
    const float* src = (set < 7)? ((mat==0)? gih + (size_t)set*28227 : ghh + (size_t)set*28227)
                                : ((mat==0)? mih : mhh);
    val = src[k*291 + j*97 + g];
  }
  u16 hi = f2b(val);
  out[idx] = (term==0)? hi : f2b(val - b2f(hi));
}

__global__ void k_pack_gatw(const float* __restrict__ gatW, u16* __restrict__ out){
  int idx = blockIdx.x*256 + threadIdx.x;
  if (idx >= 2*4*8*512) return;
  int e = idx & 7, lane = (idx>>3) & 63, t = (idx>>9) & 7;
  int ks = (idx>>12) & 3, term = idx>>14;
  int k = ks*32 + (lane>>4)*8 + e;
  int h = t*16 + (lane & 15);
  float val = (k < HH && h < HH)? gatW[k*97 + h] : 0.f;
  u16 hi = f2b(val);
  out[idx] = (term==0)? hi : f2b(val - b2f(hi));
}

// fp32 row-96 vectors: W96C[7][512], W96I[8][384], W96H[8][384] (j*128+g layout)
__global__ void k_pack_w96(const float* __restrict__ Wk, const float* __restrict__ Wq,
                           const float* __restrict__ Wv, const float* __restrict__ Ws,
                           const float* __restrict__ gih, const float* __restrict__ ghh,
                           const float* __restrict__ mih, const float* __restrict__ mhh,
                           float* __restrict__ out){
  int idx = blockIdx.x*256 + threadIdx.x;
  if (idx < 7*512){
    int l = idx >> 9, c = idx & 511;
    int m = c >> 7, h = c & 127;
    float v = 0.f;
    if (h < HH){
      const float* W = (m==0)? Wk : (m==1)? Wq : (m==2)? Wv : Ws;
      v = W[l*9409 + 96*97 + h];
    }
    out[idx] = v;
  } else if (idx < 7*512 + 8*384){
    int r = idx - 7*512;
    int set = r / 384, n = r % 384;
    int j = n >> 7, g = n & 127;
    float v = 0.f;
    if (g < HH){
      const float* srcp = (set < 7)? gih + (size_t)set*28227 : mih;
      v = srcp[96*291 + j*97 + g];
    }
    out[idx] = v;
  } else if (idx < 7*512 + 16*384){
    int r = idx - 7*512 - 8*384;
    int set = r / 384, n = r % 384;
    int j = n >> 7, g = n & 127;
    float v = 0.f;
    if (g < HH){
      const float* srcp = (set < 7)? ghh + (size_t)set*28227 : mhh;
      v = srcp[96*291 + j*97 + g];
    }
    out[idx] = v;
  }
}

__global__ void k_pack_convb(const float* __restrict__ bk, const float* __restrict__ bq,
                             const float* __restrict__ bv, const float* __restrict__ bs,
                             float* __restrict__ out){
  int idx = blockIdx.x*256 + threadIdx.x;
  if (idx >= 7*512) return;
  int l = idx >> 9, c = idx & 511;
  int m = c >> 7, h = c & 127;
  float v = 0.f;
  if (h < HH){
    const float* B = (m==0)? bk : (m==1)? bq : (m==2)? bv : bs;
    v = B[l*97 + h];
  }
  out[idx] = v;
}

__global__ void k_pack_grub(const float* __restrict__ gbi, const float* __restrict__ gbh,
                            const float* __restrict__ mbi, const float* __restrict__ mbh,
                            float* __restrict__ obi, float* __restrict__ obh){
  int idx = blockIdx.x*256 + threadIdx.x;
  if (idx >= 8*384) return;
  int set = idx / 384, n = idx % 384;
  int j = n>>7, g = n & 127;
  float vi = 0.f, vh = 0.f;
  if (g < HH){
    const float* si = (set < 7)? gbi + set*291 : mbi;
    const float* sh = (set < 7)? gbh + set*291 : mbh;
    vi = si[j*97 + g];
    vh = sh[j*97 + g];
  }
  obi[idx] = vi; obh[idx] = vh;
}

// contiguous region: GATWP[16384] ASRCP[128] ADSTP[128] GBP[128] W2P[128] pad[512]
__global__ void k_pack_misc(const float* __restrict__ gatW, const float* __restrict__ asrc,
                            const float* __restrict__ adst, const float* __restrict__ gatb,
                            const float* __restrict__ l2W, float* __restrict__ out){
  int idx = blockIdx.x*256 + threadIdx.x;
  if (idx < 16384){
    int k = idx >> 7, h = idx & 127;
    out[idx] = (k < HH && h < HH)? gatW[k*97 + h] : 0.f;
  } else if (idx < 16512){
    int h = idx - 16384; out[idx] = (h < HH)? asrc[h] : 0.f;
  } else if (idx < 16640){
    int h = idx - 16512; out[idx] = (h < HH)? adst[h] : 0.f;
  } else if (idx < 16768){
    int h = idx - 16640; out[idx] = (h < HH)? gatb[h] : 0.f;
  } else if (idx < 16896){
    int h = idx - 16768; out[idx] = (h < HH)? l2W[h] : 0.f;
  } else if (idx < 17408){
    out[idx] = 0.f;
  }
}

// ============ graph preprocessing ============
__global__ void k_seg(const int* __restrict__ batch, int* __restrict__ seg){
  int g = blockIdx.x*blockDim.x + threadIdx.x;
  if (g > NG) return;
  int lo = 0, hi = NN;
  while (lo < hi){ int mid = (lo+hi) >> 1; if (batch[mid] < g) lo = mid+1; else hi = mid; }
  seg[g] = lo;
}

__global__ void k_hist(const int* __restrict__ dst, int* __restrict__ cnt){
  int e = blockIdx.x*256 + threadIdx.x;
  if (e < NE) atomicAdd(&cnt[dst[e]], 1);
}

__global__ void k_scan_blk(const int* __restrict__ cnt, int* __restrict__ offs,
                           int* __restrict__ bsum){
  __shared__ int s[256];
  int b = blockIdx.x, t = threadIdx.x, i = b*256 + t;
  int v = (i < NN)? cnt[i] : 0;
  s[t] = v; __syncthreads();
  #pragma unroll
  for (int off = 1; off < 256; off <<= 1){
    int tmp = (t >= off)? s[t-off] : 0;
    __syncthreads();
    s[t] += tmp;
    __syncthreads();
  }
  if (i < NN) offs[i] = s[t] - v;
  if (t == 255) bsum[b] = s[255];
}

__global__ void k_scan_top(int* __restrict__ bsum){
  __shared__ int s[512];
  int t = threadIdx.x;
  int v = (t < NB)? bsum[t] : 0;
  s[t] = v; __syncthreads();
  #pragma unroll
  for (int off = 1; off < 512; off <<= 1){
    int tmp = (t >= off)? s[t-off] : 0;
    __syncthreads();
    s[t] += tmp;
    __syncthreads();
  }
  if (t < NB) bsum[t] = s[t] - v;
}

__global__ void k_scan_add(int* __restrict__ offs, const int* __restrict__ bsum,
                           int* __restrict__ cur){
  int b = blockIdx.x, t = threadIdx.x, i = b*256 + t;
  if (i < NN){ int o = offs[i] + bsum[b]; offs[i] = o; cur[i] = o; }
  if (i == 0) offs[NN] = NE;
}

__global__ void k_scatter(const int* __restrict__ src, const int* __restrict__ dst,
                          int* __restrict__ cur, int* __restrict__ eidx){
  int e = blockIdx.x*256 + threadIdx.x;
  if (e >= NE) return;
  int pos = atomicAdd(&cur[dst[e]], 1);
  eidx[pos] = src[e];
}

// ============ lin1 (covers NNP rows; pad rows -> 0) ============
__global__ __launch_bounds__(256) void k_lin1(const float* __restrict__ x,
    const float* __restrict__ W, const float* __restrict__ b, u16* __restrict__ X0){
  int idx = blockIdx.x*256 + threadIdx.x;
  int n = idx >> 7, c = idx & 127;
  float v = 0.f;
  if (n < NN && c < HH){
    v = b[c];
    #pragma unroll
    for (int k = 0; k < 9; ++k) v += x[n*9 + k]*W[k*HH + c];
    v = lrelu01_(v);
  }
  X0[(size_t)n*HP + c] = f2b(v);
}

// ============ conv GEMM (MFMA): 64 rows/block, ks=0..2 + k96 epilogue ============
__global__ __launch_bounds__(256) void k_conv_mfma(const u16* __restrict__ X,
    const u16* __restrict__ WCF_l, const float* __restrict__ biasp,
    const float* __restrict__ W96C, u16* __restrict__ KQV, float* __restrict__ S){
  int tid = threadIdx.x;
  int w = tid >> 6, lane = tid & 63;
  int lm = lane & 15, ls = lane >> 4;
  int m0 = blockIdx.x*64;
  f32x4 acc[4][8] = {};
  for (int ks = 0; ks < 3; ++ks){
    short8v aX[4];
    #pragma unroll
    for (int rb = 0; rb < 4; ++rb)
      aX[rb] = *(const short8v*)(X + (size_t)(m0 + rb*16 + lm)*HP + ks*32 + ls*8);
    short8v wf[8][2];
    #pragma unroll
    for (int t = 0; t < 8; ++t){
      int tg = w*8 + t;
      wf[t][0] = *(const short8v*)(WCF_l + (((size_t)(0*4 + ks)*32 + tg)*64 + lane)*8);
      wf[t][1] = *(const short8v*)(WCF_l + (((size_t)(1*4 + ks)*32 + tg)*64 + lane)*8);
    }
    #pragma unroll
    for (int t = 0; t < 8; ++t)
      #pragma unroll
      for (int rb = 0; rb < 4; ++rb){
        acc[rb][t] = mfma16(aX[rb], wf[t][0], acc[rb][t]);
        acc[rb][t] = mfma16(aX[rb], wf[t][1], acc[rb][t]);
      }
  }
  // epilogue: + bias + X[row][96]*W96C[col]
  float x96[4][4];
  #pragma unroll
  for (int rb = 0; rb < 4; ++rb)
    #pragma unroll
    for (int r = 0; r < 4; ++r)
      x96[rb][r] = b2f(X[(size_t)(m0 + rb*16 + ls*4 + r)*HP + 96]);
  #pragma unroll
  for (int t = 0; t < 8; ++t){
    int c = t*16 + lm;
    int col = w*128 + c;
    float bv = biasp[col];
    float w96 = W96C[col];
    #pragma unroll
    for (int rb = 0; rb < 4; ++rb)
      #pragma unroll
      for (int r = 0; r < 4; ++r){
        int row = m0 + rb*16 + ls*4 + r;
        float v = acc[rb][t][r] + bv + x96[rb][r]*w96;
        if (w < 3) KQV[(size_t)row*384 + w*128 + c] = f2b(v);
        else       S[(size_t)row*HP + c] = v;
      }
  }
}

// ============ GRU GEMM+gates (MFMA): ks=0..2 + k96 epilogue ============
__global__ __launch_bounds__(256) void k_gru_mfma(const float* __restrict__ Hin,
    const u16* __restrict__ Xin, const u16* __restrict__ WGF_set,
    const float* __restrict__ bihp, const float* __restrict__ bhhp,
    const float* __restrict__ W96I, const float* __restrict__ W96H,
    u16* __restrict__ Xout){
  int tid = threadIdx.x;
  int w = tid >> 6, lane = tid & 63;
  int lm = lane & 15, ls = lane >> 4;
  int m0 = blockIdx.x*32;
  f32x4 agi[2][2][3] = {};
  f32x4 agh[2][2][3] = {};
  for (int ks = 0; ks < 3; ++ks){
    short8v aX[2], aSh[2], aSl[2];
    #pragma unroll
    for (int rb = 0; rb < 2; ++rb){
      int row = m0 + rb*16 + lm;
      aX[rb] = *(const short8v*)(Xin + (size_t)row*HP + ks*32 + ls*8);
      const float* sp = Hin + (size_t)row*HP + ks*32 + ls*8;
      float sv[8];
      *(float4*)&sv[0] = *(const float4*)sp;
      *(float4*)&sv[4] = *(const float4*)(sp + 4);
      short8v vh, vl;
      #pragma unroll
      for (int e = 0; e < 8; ++e){
        u16 hb = f2b(sv[e]);
        vh[e] = (short)hb;
        vl[e] = (short)f2b(sv[e] - b2f(hb));
      }
      aSh[rb] = vh; aSl[rb] = vl;
    }
    #pragma unroll
    for (int b = 0; b < 2; ++b){
      short8v fI[3][2], fH[3][2];
      #pragma unroll
      for (int j = 0; j < 3; ++j){
        int t = j*8 + 2*w + b;
        fI[j][0] = *(const short8v*)(WGF_set + (((size_t)(0*4 + ks)*24 + t)*64 + lane)*8);
        fI[j][1] = *(const short8v*)(WGF_set + (((size_t)(1*4 + ks)*24 + t)*64 + lane)*8);
        fH[j][0] = *(const short8v*)(WGF_set + (((size_t)(2*4 + ks)*24 + t)*64 + lane)*8);
        fH[j][1] = *(const short8v*)(WGF_set + (((size_t)(3*4 + ks)*24 + t)*64 + lane)*8);
      }
      #pragma unroll
      for (int j = 0; j < 3; ++j)
        #pragma unroll
        for (int rb = 0; rb < 2; ++rb){
          agi[rb][b][j] = mfma16(aSh[rb], fI[j][0], agi[rb][b][j]);
          agi[rb][b][j] = mfma16(aSh[rb], fI[j][1], agi[rb][b][j]);
          agi[rb][b][j] = mfma16(aSl[rb], fI[j][0], agi[rb][b][j]);
          agh[rb][b][j] = mfma16(aX[rb], fH[j][0], agh[rb][b][j]);
          agh[rb][b][j] = mfma16(aX[rb], fH[j][1], agh[rb][b][j]);
        }
    }
  }
  // epilogue: k=96 contribution in exact fp32, then gates
  float s96[2][4], x96[2][4];
  #pragma unroll
  for (int rb = 0; rb < 2; ++rb)
    #pragma unroll
    for (int r = 0; r < 4; ++r){
      int row = m0 + rb*16 + ls*4 + r;
      s96[rb][r] = Hin[(size_t)row*HP + 96];
      x96[rb][r] = b2f(Xin[(size_t)row*HP + 96]);
    }
  #pragma unroll
  for (int b = 0; b < 2; ++b){
    int g = (2*w + b)*16 + lm;
    float bi0 = bihp[g], bi1 = bihp[128+g], bi2 = bihp[256+g];
    float bh0 = bhhp[g], bh1 = bhhp[128+g], bh2 = bhhp[256+g];
    float wi0 = W96I[g], wi1 = W96I[128+g], wi2 = W96I[256+g];
    float wh0 = W96H[g], wh1 = W96H[128+g], wh2 = W96H[256+g];
    #pragma unroll
    for (int rb = 0; rb < 2; ++rb)
      #pragma unroll
      for (int r = 0; r < 4; ++r){
        int row = m0 + rb*16 + ls*4 + r;
        float ir = agi[rb][b][0][r] + bi0 + s96[rb][r]*wi0;
        float iz = agi[rb][b][1][r] + bi1 + s96[rb][r]*wi1;
        float in_ = agi[rb][b][2][r] + bi2 + s96[rb][r]*wi2;
        float hr = agh[rb][b][0][r] + bh0 + x96[rb][r]*wh0;
        float hz = agh[rb][b][1][r] + bh1 + x96[rb][r]*wh1;
        float hn = agh[rb][b][2][r] + bh2 + x96[rb][r]*wh2;
        float rr = sigm_(ir + hr);
        float zz = sigm_(iz + hz);
        float nn2 = tanh_(in_ + rr*hn);
        float xo = b2f(Xin[(size_t)row*HP + g]);
        float v = (1.f - zz)*nn2 + zz*xo;
        Xout[(size_t)row*HP + g] = f2b(fmaxf(v, 0.f));
      }
  }
}

// ============ plain 128-col GEMM (MFMA): XS = X @ gatW ============
__global__ __launch_bounds__(256) void k_xs_mfma(const u16* __restrict__ X,
    const u16* __restrict__ GATF, u16* __restrict__ XS){
  int tid = threadIdx.x;
  int w = tid >> 6, lane = tid & 63;
  int lm = lane & 15, ls = lane >> 4;
  int m0 = blockIdx.x*32;
  f32x4 acc[2][2] = {};
  for (int ks = 0; ks < 4; ++ks){
    short8v aX[2];
    #pragma unroll
    for (int rb = 0; rb < 2; ++rb){
      int row = m0 + rb*16 + lm;
      aX[rb] = *(const short8v*)(X + (size_t)row*HP + ks*32 + ls*8);
    }
    #pragma unroll
    for (int b = 0; b < 2; ++b){
      int t = 2*w + b;
      short8v bh = *(const short8v*)(GATF + (((size_t)(0*4 + ks)*8 + t)*64 + lane)*8);
      short8v bl = *(const short8v*)(GATF + (((size_t)(1*4 + ks)*8 + t)*64 + lane)*8);
      #pragma unroll
      for (int rb = 0; rb < 2; ++rb){
        acc[rb][b] = mfma16(aX[rb], bh, acc[rb][b]);
        acc[rb][b] = mfma16(aX[rb], bl, acc[rb][b]);
      }
    }
  }
  #pragma unroll
  for (int b = 0; b < 2; ++b){
    int c = (2*w + b)*16 + lm;
    #pragma unroll
    for (int rb = 0; rb < 2; ++rb)
      #pragma unroll
      for (int r = 0; r < 4; ++r){
        int row = m0 + rb*16 + ls*4 + r;
        XS[(size_t)row*HP + c] = f2b(acc[rb][b][r]);
      }
  }
}

// ============ CSR aggregation (+ residual + ELU + BN), one wave per dst node ============
__global__ __launch_bounds__(256) void k_agg(const u16* __restrict__ kqv,
    const int* __restrict__ offs, const int* __restrict__ eidx,
    float* __restrict__ S, const float* __restrict__ gamma, const float* __restrict__ beta,
    const float* __restrict__ mean, const float* __restrict__ var, int layer){
  int n = blockIdx.x*4 + (threadIdx.x >> 6);
  if (n >= NN) return;
  int lane = threadIdx.x & 63;
  int c2 = lane*2;
  int lo = offs[n], hi = offs[n+1];
  ushort2 kk = *(const ushort2*)(kqv + (size_t)n*384 + c2);
  float k0 = b2f(kk.x), k1 = b2f(kk.y);
  float a0 = 0.f, a1 = 0.f;
  int i = lo;
  for (; i + 4 <= hi; i += 4){
    int s0 = eidx[i], s1 = eidx[i+1], s2 = eidx[i+2], s3 = eidx[i+3];
    const u16* q0 = kqv + (size_t)s0*384 + 128 + c2;
    const u16* q1 = kqv + (size_t)s1*384 + 128 + c2;
    const u16* q2 = kqv + (size_t)s2*384 + 128 + c2;
    const u16* q3 = kqv + (size_t)s3*384 + 128 + c2;
    ushort2 qa = *(const ushort2*)q0, va = *(const ushort2*)(q0 + 128);
    ushort2 qb = *(const ushort2*)q1, vb = *(const ushort2*)(q1 + 128);
    ushort2 qc = *(const ushort2*)q2, vc = *(const ushort2*)(q2 + 128);
    ushort2 qd = *(const ushort2*)q3, vd = *(const ushort2*)(q3 + 128);
    a0 += b2f(va.x)*sigm_(k0 + b2f(qa.x)); a1 += b2f(va.y)*sigm_(k1 + b2f(qa.y));
    a0 += b2f(vb.x)*sigm_(k0 + b2f(qb.x)); a1 += b2f(vb.y)*sigm_(k1 + b2f(qb.y));
    a0 += b2f(vc.x)*sigm_(k0 + b2f(qc.x)); a1 += b2f(vc.y)*sigm_(k1 + b2f(qc.y));
    a0 += b2f(vd.x)*sigm_(k0 + b2f(qd.x)); a1 += b2f(vd.y)*sigm_(k1 + b2f(qd.y));
  }
  for (; i < hi; ++i){
    int s = eidx[i];
    const u16* qb0 = kqv + (size_t)s*384 + 128 + c2;
    ushort2 qq = *(const ushort2*)qb0;
    ushort2 vv = *(const ushort2*)(qb0 + 128);
    a0 += b2f(vv.x)*sigm_(k0 + b2f(qq.x));
    a1 += b2f(vv.y)*sigm_(k1 + b2f(qq.y));
  }
  float* sp = S + (size_t)n*HP + c2;
  float2 sr = *(float2*)sp;
  float v0 = sr.x + a0, v1 = sr.y + a1;
  v0 = v0 > 0.f ? v0 : (__expf(v0) - 1.f);
  v1 = v1 > 0.f ? v1 : (__expf(v1) - 1.f);
  if (layer > 0){
    int b0 = (layer-1)*97 + c2;
    if (c2 < HH){ float sc = gamma[b0]*rsqrtf(var[b0] + 1e-5f); v0 = (v0 - mean[b0])*sc + beta[b0]; }
    if (c2+1 < HH){ float sc = gamma[b0+1]*rsqrtf(var[b0+1] + 1e-5f); v1 = (v1 - mean[b0+1])*sc + beta[b0+1]; }
  }
  if (c2 >= HH)   v0 = 0.f;
  if (c2+1 >= HH) v1 = 0.f;
  *(float2*)sp = make_float2(v0, v1);
}

// ============ readout ============
__global__ __launch_bounds__(128) void k_pool(const int* __restrict__ seg,
    const u16* __restrict__ x, u16* __restrict__ out){
  int g = blockIdx.x, tid = threadIdx.x;
  int lo = seg[g], hi = seg[g+1];
  float acc = 0.f;
  for (int n = lo; n < hi; ++n) acc += b2f(x[(size_t)n*HP + tid]);
  out[(size_t)g*HP + tid] = f2b(fmaxf(acc, 0.f));
}

__global__ __launch_bounds__(256) void k_as(const u16* __restrict__ xs,
    const float* __restrict__ asrcp, float* __restrict__ a_s){
  int t = blockIdx.x*256 + threadIdx.x;
  int n = t >> 6, lane = t & 63;
  float v = b2f(xs[(size_t)n*HP + lane])*asrcp[lane]
          + b2f(xs[(size_t)n*HP + 64 + lane])*asrcp[64 + lane];
  #pragma unroll
  for (int o = 32; o > 0; o >>= 1) v += __shfl_down(v, o);
  if (lane == 0) a_s[n] = v;
}

__global__ __launch_bounds__(128) void k_ad(const u16* __restrict__ out,
    const float* __restrict__ gatwp, const float* __restrict__ adstp, float* __restrict__ ad){
  int g = blockIdx.x, tid = threadIdx.x;
  __shared__ float so[HP];
  __shared__ float red[2];
  so[tid] = b2f(out[(size_t)g*HP + tid]);
  __syncthreads();
  float p = 0.f;
  #pragma unroll 4
  for (int k = 0; k < HP; ++k) p += so[k]*gatwp[k*HP + tid];
  float v = p * adstp[tid];
  #pragma unroll
  for (int o = 32; o > 0; o >>= 1) v += __shfl_down(v, o);
  if ((tid & 63) == 0) red[tid >> 6] = v;
  __syncthreads();
  if (tid == 0) ad[g] = red[0] + red[1];
}

#define ACAP 2048
__global__ __launch_bounds__(128) void k_attn(const int* __restrict__ seg,
    const float* __restrict__ a_s, const float* __restrict__ a_d,
    const u16* __restrict__ xs, const float* __restrict__ gbp, float* __restrict__ hg){
  int g = blockIdx.x, tid = threadIdx.x;
  int lo = seg[g], hi = seg[g+1], cnt = hi - lo;
  float ad = a_d[g];
  __shared__ float sa[ACAP];
  __shared__ float red[2];
  float mloc = -3.4e38f;
  for (int i = tid; i < cnt; i += 128){
    float al = lrelu01_(a_s[lo+i] + ad);
    if (i < ACAP) sa[i] = al;
    mloc = fmaxf(mloc, al);
  }
  #pragma unroll
  for (int o = 32; o > 0; o >>= 1) mloc = fmaxf(mloc, __shfl_down(mloc, o));
  if ((tid & 63) == 0) red[tid >> 6] = mloc;
  __syncthreads();
  float mm = fmaxf(red[0], red[1]);
  __syncthreads();
  float sloc = 0.f;
  for (int i = tid; i < cnt; i += 128){
    float al = (i < ACAP)? sa[i] : lrelu01_(a_s[lo+i] + ad);
    float e = __expf(al - mm);
    if (i < ACAP) sa[i] = e;
    sloc += e;
  }
  #pragma unroll
  for (int o = 32; o > 0; o >>= 1) sloc += __shfl_down(sloc, o);
  if ((tid & 63) == 0) red[tid >> 6] = sloc;
  __syncthreads();
  float ss = red[0] + red[1];
  float inv = (cnt > 0 && ss != 0.f)? 1.f/ss : 0.f;
  __syncthreads();
  float accv = 0.f;
  for (int i = 0; i < cnt; ++i){
    float e = (i < ACAP)? sa[i] : __expf(lrelu01_(a_s[lo+i] + ad) - mm);
    accv += (e*inv) * b2f(xs[(size_t)(lo+i)*HP + tid]);
  }
  float hgv = accv + gbp[tid];
  hg[(size_t)g*HP + tid] = hgv > 0.f ? hgv : (__expf(hgv) - 1.f);
}

__global__ __launch_bounds__(64) void k_final(const u16* __restrict__ out,
    const float* __restrict__ w2p, const float* __restrict__ l2b, float* __restrict__ y){
  int g = blockIdx.x, lane = threadIdx.x;
  float v = b2f(out[(size_t)g*HP + lane])*w2p[lane]
          + b2f(out[(size_t)g*HP + 64 + lane])*w2p[64 + lane];
  #pragma unroll
  for (int o = 32; o > 0; o >>= 1) v += __shfl_down(v, o);
  if (lane == 0) y[g] = v + l2b[0];
}

// ============ host ============
extern "C" void kernel_launch(void* const* d_in, const int* in_sizes, int n_in,
                              void* d_out, int out_size, void* d_ws, size_t ws_size,
                              hipStream_t stream){
  const float* x_in  = (const float*)d_in[0];
  const int*   ei    = (const int*)d_in[1];
  const int*   batch = (const int*)d_in[2];
  const float* lin1W = (const float*)d_in[4];
  const float* lin1b = (const float*)d_in[5];
  const float* cWk = (const float*)d_in[6];
  const float* cWq = (const float*)d_in[7];
  const float* cWv = (const float*)d_in[8];
  const float* cWs = (const float*)d_in[9];
  const float* cbk = (const float*)d_in[10];
  const float* cbq = (const float*)d_in[11];
  const float* cbv = (const float*)d_in[12];
  const float* cbs = (const float*)d_in[13];
  const float* gWih = (const float*)d_in[14];
  const float* gWhh = (const float*)d_in[15];
  const float* gbih = (const float*)d_in[16];
  const float* gbhh = (const float*)d_in[17];
  const float* bng = (const float*)d_in[18];
  const float* bnb = (const float*)d_in[19];
  const float* bnm = (const float*)d_in[20];
  const float* bnv = (const float*)d_in[21];
  const float* gatW  = (const float*)d_in[22];
  const float* gasrc = (const float*)d_in[23];
  const float* gadst = (const float*)d_in[24];
  const float* gatb  = (const float*)d_in[25];
  const float* mWih = (const float*)d_in[26];
  const float* mWhh = (const float*)d_in[27];
  const float* mbih = (const float*)d_in[28];
  const float* mbhh = (const float*)d_in[29];
  const float* l2W = (const float*)d_in[30];
  const float* l2b = (const float*)d_in[31];
  const int* src = ei;
  const int* dst = ei + NE;

  char* base = (char*)d_ws;
  size_t off = 0;
  auto alloc = [&](size_t nbytes)->char*{
    char* p = base + off; off = (off + nbytes + 255) & ~(size_t)255; return p; };

  u16*  WCF  = (u16*)alloc((size_t)7*2*4*32*512*2);
  u16*  WGF  = (u16*)alloc((size_t)8*2*2*4*24*512*2);
  u16*  GATF = (u16*)alloc((size_t)2*4*8*512*2);
  float* W96  = (float*)alloc((size_t)(7*512 + 16*384)*4);  // W96C | W96I | W96H
  float* BCONVP = (float*)alloc(7*512*4);
  float* BIHP   = (float*)alloc(8*384*4);
  float* BHHP   = (float*)alloc(8*384*4);
  float* GATWP  = (float*)alloc(17408*4);
  float* ASRCP = GATWP + 16384;
  float* ADSTP = GATWP + 16512;
  float* GBP   = GATWP + 16640;
  float* W2P   = GATWP + 16768;
  u16*  X0  = (u16*)alloc((size_t)NNP*HP*2);
  u16*  X1  = (u16*)alloc((size_t)NNP*HP*2);
  u16*  KQV = (u16*)alloc((size_t)NNP*384*2);
  float* S  = (float*)alloc((size_t)NNP*HP*4);
  float* AS_ = (float*)alloc((size_t)NN*4);
  float* AD_ = (float*)alloc((size_t)NG*4);
  u16*  OUTA = (u16*)alloc((size_t)NG*HP*2);
  u16*  OUTB = (u16*)alloc((size_t)NG*HP*2);
  float* HG  = (float*)alloc((size_t)NG*HP*4);
  int*  SEG  = (int*)alloc((size_t)(NG+1)*4);
  int*  CNT  = (int*)alloc((size_t)NN*4);
  int*  OFFS = (int*)alloc((size_t)(NN+1)*4);
  int*  CUR  = (int*)alloc((size_t)NN*4);
  int*  EIDX = (int*)alloc((size_t)NE*4);
  int*  BSUM = (int*)alloc((size_t)NB*4);

  float* W96C = W96;
  float* W96I = W96 + 7*512;
  float* W96H = W96 + 7*512 + 8*384;

  if (ws_size < off){
    hipMemsetAsync(d_out, 0, (size_t)out_size*sizeof(float), stream);
    return;
  }

  // ---- one-time packing + graph prep ----
  k_pack_convw<<<(7*2*4*32*512+255)/256,256,0,stream>>>(cWk,cWq,cWv,cWs,WCF);
  k_pack_gruw<<<(8*2*2*4*24*512+255)/256,256,0,stream>>>(gWih,gWhh,mWih,mWhh,WGF);
  k_pack_gatw<<<(2*4*8*512+255)/256,256,0,stream>>>(gatW,GATF);
  k_pack_w96<<<(7*512+16*384+255)/256,256,0,stream>>>(cWk,cWq,cWv,cWs,gWih,gWhh,mWih,mWhh,W96);
  k_pack_convb<<<(7*512+255)/256,256,0,stream>>>(cbk,cbq,cbv,cbs,BCONVP);
  k_pack_grub<<<(8*384+255)/256,256,0,stream>>>(gbih,gbhh,mbih,mbhh,BIHP,BHHP);
  k_pack_misc<<<68,256,0,stream>>>(gatW,gasrc,gadst,gatb,l2W,GATWP);
  k_lin1<<<(NNP*HP)/256,256,0,stream>>>(x_in,lin1W,lin1b,X0);
  k_seg<<<(NG+1+255)/256,256,0,stream>>>(batch,SEG);

  hipMemsetAsync(CNT, 0, (size_t)NN*4, stream);
  k_hist<<<(NE+255)/256,256,0,stream>>>(dst, CNT);
  k_scan_blk<<<NB,256,0,stream>>>(CNT, OFFS, BSUM);
  k_scan_top<<<1,512,0,stream>>>(BSUM);
  k_scan_add<<<NB,256,0,stream>>>(OFFS, BSUM, CUR);
  k_scatter<<<(NE+255)/256,256,0,stream>>>(src, dst, CUR, EIDX);

  // ---- 7 conv+gru layers ----
  for (int l = 0; l < 7; ++l){
    u16* Xin  = (l & 1)? X1 : X0;
    u16* Xout = (l & 1)? X0 : X1;
    k_conv_mfma<<<NNP/64,256,0,stream>>>(Xin, WCF + (size_t)l*131072, BCONVP + l*512,
                                         W96C + l*512, KQV, S);
    k_agg<<<(NN+3)/4,256,0,stream>>>(KQV, OFFS, EIDX, S, bng, bnb, bnm, bnv, l);
    k_gru_mfma<<<NNP/32,256,0,stream>>>(S, Xin, WGF + (size_t)l*196608,
                                        BIHP + l*384, BHHP + l*384,
                                        W96I + l*384, W96H + l*384, Xout);
  }
  u16* XF = X1;

  // ---- readout ----
  k_pool<<<NG,128,0,stream>>>(SEG, XF, OUTA);
  u16* XS = KQV;
  k_xs_mfma<<<NNP/32,256,0,stream>>>(XF, GATF, XS);
  k_as<<<(NN*64)/256,256,0,stream>>>(XS, ASRCP, AS_);

  u16* cur = OUTA; u16* nxt = OUTB;
  for (int s = 0; s < 7; ++s){
    k_ad<<<NG,128,0,stream>>>(cur, GATWP, ADSTP, AD_);
    k_attn<<<NG,128,0,stream>>>(SEG, AS_, AD_, XS, GBP, HG);
    k_gru_mfma<<<NG/32,256,0,stream>>>(HG, cur, WGF + (size_t)7*196608,
                                       BIHP + 7*384, BHHP + 7*384,
                                       W96I + 7*384, W96H + 7*384, nxt);
    u16* t = cur; cur = nxt; nxt = t;
  }
  k_final<<<NG,64,0,stream>>>(cur, W2P, l2b, (float*)d_out);
}